// Round 7
// baseline (436.049 us; speedup 1.0000x reference)
//
#include <hip/hip_runtime.h>
#include <stdint.h>

typedef __attribute__((ext_vector_type(8))) short bf16x8;
typedef __attribute__((ext_vector_type(4))) float f32x4;

__device__ __forceinline__ float bf2f(ushort h) {
    union { uint u; float f; } v; v.u = ((uint)h) << 16; return v.f;
}
__device__ __forceinline__ ushort f2bf(float f) {
    union { float f; uint u; } v; v.f = f;
    uint u = v.u;
    return (ushort)((u + 0x7fffu + ((u >> 16) & 1u)) >> 16);
}

// async global->LDS, 16B per lane; LDS dest = wave-uniform base + lane*16
__device__ __forceinline__ void gll(const ushort* g, ushort* l) {
    __builtin_amdgcn_global_load_lds(
        (const __attribute__((address_space(1))) void*)g,
        (__attribute__((address_space(3))) void*)l, 16, 0, 0);
}

// ---------------- prep: classify nodes + x->bf16 (padded to 128 cols) ----------------

__global__ void k_prep(const uint* __restrict__ xu, const uint* __restrict__ nfu,
                       ushort* __restrict__ xb, int* __restrict__ gid,
                       unsigned char* __restrict__ gidb, int NN) {
    int wid = blockIdx.x * 4 + (threadIdx.x >> 6);
    int lane = threadIdx.x & 63;
    if (wid >= NN) return;
    int c0 = lane * 2;
    uint w = 0u;
    int m0 = 1, m1 = 1, m2 = 1;
    if (c0 < 100) {
        uint2 xv = *(const uint2*)&xu[(size_t)wid * 100 + c0];
        uint2 a = *(const uint2*)&nfu[c0];
        uint2 bb = *(const uint2*)&nfu[100 + c0];
        uint2 c = *(const uint2*)&nfu[200 + c0];
        m0 = (xv.x == a.x) & (xv.y == a.y);
        m1 = (xv.x == bb.x) & (xv.y == bb.y);
        m2 = (xv.x == c.x) & (xv.y == c.y);
        w = (uint)f2bf(__uint_as_float(xv.x)) | ((uint)f2bf(__uint_as_float(xv.y)) << 16);
    }
    int e0 = __all(m0), e1 = __all(m1), e2 = __all(m2);
    *(uint*)&xb[(size_t)wid * 128 + c0] = w;
    if (lane == 0) {
        // group id for the output reduction: 0/3/1/2 mapping (unchanged)
        gid[wid] = e0 ? 0 : (e1 ? 3 : (e2 ? 1 : 2));
        // prototype id for agg1: 0,1,2 = nf row index, 3 = random features
        gidb[wid] = (unsigned char)(e0 ? 0 : (e1 ? 1 : (e2 ? 2 : 3)));
    }
}

// ---------------- deg: per-dst counters split by src class (type3 | proto) ----------------
// slot[e] = within-class slot | (ptype<<28). Type-3 edges get slots [0,d3),
// proto edges [d3,deg) -> agg1 runs a dense gather segment + a norm-only segment.

__global__ void k_deg(const int* __restrict__ src, const int* __restrict__ dst, int E,
                      const unsigned char* __restrict__ gidb,
                      int* __restrict__ cnt3, int* __restrict__ cntP,
                      int* __restrict__ slot) {
    int e = blockIdx.x * 256 + threadIdx.x;
    if (e >= E) return;
    int d = dst[e];
    int t = gidb[src[e]];  // 50KB table, L1/L2-hot
    int s;
    if (t == 3) s = atomicAdd(&cnt3[d], 1);
    else        s = atomicAdd(&cntP[d], 1);
    slot[e] = s | (t << 28);
}

// ---------------- wsplit: W -> bf16 hi/lo transposed planes ----------------

__device__ __forceinline__ void tr2_one(const float* __restrict__ W,
                                        ushort* __restrict__ WTh, ushort* __restrict__ WTl,
                                        int K, int Nc, int KP, int idx) {
    int n = idx / KP, k = idx % KP;
    float w = (n < Nc && k < K) ? W[(size_t)k * Nc + n] : 0.0f;
    ushort hi = f2bf(w);
    ushort lo = f2bf(w - bf2f(hi));
    WTh[idx] = hi;
    WTl[idx] = lo;
}

__global__ void k_wsplit(const float* __restrict__ W1, const float* __restrict__ W2,
                         const float* __restrict__ W3, const float* __restrict__ W4,
                         ushort* __restrict__ WT1h, ushort* __restrict__ WT1l,
                         ushort* __restrict__ WT2h, ushort* __restrict__ WT2l,
                         ushort* __restrict__ WT3h, ushort* __restrict__ WT3l,
                         ushort* __restrict__ WT4h, ushort* __restrict__ WT4l) {
    int idx = blockIdx.x * 256 + threadIdx.x;
    if (idx < 65536) tr2_one(W1, WT1h, WT1l, 100, 512, 128, idx);
    else if (idx < 196608) tr2_one(W2, WT2h, WT2l, 512, 256, 512, idx - 65536);
    else if (idx < 229376) tr2_one(W3, WT3h, WT3l, 256, 128, 256, idx - 196608);
    else if (idx < 262144) tr2_one(W4, WT4h, WT4l, 128, 200, 128, idx - 229376);
}

// ---------------- scanA: block-local prefix + dinv + group counts ----------------

__global__ void k_scanA(const int* __restrict__ cnt3, const int* __restrict__ cntP,
                        int* __restrict__ degT, int* __restrict__ offs,
                        int* __restrict__ bsum, float* __restrict__ dinv,
                        const int* __restrict__ gid, int* __restrict__ gcnt, int NN) {
    __shared__ int lds[256];
    __shared__ int cnt4[4];
    int t = threadIdx.x;
    if (t < 4) cnt4[t] = 0;
    int i = blockIdx.x * 256 + t;
    int v = (i < NN) ? (cnt3[i] + cntP[i]) : 0;
    if (i < NN) {
        degT[i] = v;
        dinv[i] = 1.0f / sqrtf((float)(v + 1));  // +1 self loop
    }
    lds[t] = v;
    __syncthreads();
    if (i < NN) atomicAdd(&cnt4[gid[i]], 1);
    for (int d = 1; d < 256; d <<= 1) {
        int u = (t >= d) ? lds[t - d] : 0;
        __syncthreads();
        lds[t] += u;
        __syncthreads();
    }
    if (i < NN) offs[i] = lds[t] - v;  // block-local exclusive
    if (t == 255) bsum[blockIdx.x] = lds[255];
    __syncthreads();
    if (t < 4 && cnt4[t]) atomicAdd(&gcnt[t], cnt4[t]);
}

// ---------------- fill: atomic-free placement, class-segmented slots ----------------

__global__ void k_fill(const int* __restrict__ src, const int* __restrict__ dst,
                       const int* __restrict__ slot, const int* __restrict__ cnt3, int E,
                       const float* __restrict__ dinv, const int* __restrict__ offs,
                       const int* __restrict__ bsum,
                       uint2* __restrict__ epk, int NN, int NB,
                       int* __restrict__ goffs) {
    __shared__ int sex[256];
    int t = threadIdx.x;
    int v = (t < NB) ? bsum[t] : 0;
    sex[t] = v;
    __syncthreads();
    for (int d = 1; d < 256; d <<= 1) {
        int u = (t >= d) ? sex[t - d] : 0;
        __syncthreads();
        sex[t] += u;
        __syncthreads();
    }
    int incl = sex[t];
    __syncthreads();
    sex[t] = incl - v;  // exclusive prefix of bsum
    __syncthreads();
    int i = blockIdx.x * 256 + t;
    if (i < NN) goffs[i] = offs[i] + sex[i >> 8];
    if (i >= E) return;
    int s = src[i], d = dst[i];
    int sl = slot[i];
    int ty = sl >> 28;
    int sp = sl & 0x0FFFFFFF;
    int base = offs[d] + sex[d >> 8];
    int p = base + ((ty == 3) ? sp : (cnt3[d] + sp));
    epk[p] = make_uint2((uint)s | ((uint)ty << 30), __float_as_uint(dinv[s] * dinv[d]));
}

// ---------------- aggregation ----------------
// r2-r5 findings: all D=256 agg variants (fetch 160-188MB, 5 different issue
// structures) run at ~59.8us; D=128 at ~half => time ~ total 64B lines
// requested (~0.42 lines/cy/CU tag/queue wall). Not HBM-BW (2.7 of 6.3 TB/s),
// not L2-BW (6.9 of 34.5), not VALU. Aggs are at their structural floor at
// bf16 row width; leave them alone.
// epk.x carries src | (ptype<<30); mask with 0x3FFFFFFF when gathering.

__device__ __forceinline__ uint2 ldnt_u2(const uint2* p) {
    union { unsigned long long ll; uint2 v; } r;
    r.ll = __builtin_nontemporal_load((const unsigned long long*)p);
    return r.v;
}

__device__ __forceinline__ void fma2(uint u, float w, float& a0, float& a1) {
    union { uint u; float f; } lo, hi;
    lo.u = u << 16;           // bf16 low element -> f32
    hi.u = u & 0xffff0000u;   // bf16 high element -> f32
    a0 = fmaf(w, lo.f, a0);
    a1 = fmaf(w, hi.f, a1);
}

template <int UN, int LD>
__device__ __forceinline__ void agg_step(const ushort* __restrict__ Hc,
                                         const uint2* __restrict__ epk, int e,
                                         float& a0, float& a1) {
    uint2 q[UN];
#pragma unroll
    for (int i = 0; i < UN; ++i) q[i] = ldnt_u2(epk + e + i);
    uint u[UN];
#pragma unroll
    for (int i = 0; i < UN; ++i)
        u[i] = *(const uint*)(Hc + (size_t)(q[i].x & 0x3FFFFFFFu) * LD);
#pragma unroll
    for (int i = 0; i < UN; ++i) fma2(u[i], __uint_as_float(q[i].y), a0, a1);
}

// One wave per node per 128-col slice; slice = blockIdx % NSL (NSL | 8) pins
// slices to XCD classes (r4: cuts fetch 187->160MB, time-neutral; kept).
template <int LD, int NSL, bool BR>
__global__ __launch_bounds__(256) void k_aggs(
        const ushort* __restrict__ H, ushort* __restrict__ outb,
        const float* __restrict__ dinv, const int* __restrict__ offs,
        const int* __restrict__ deg, const uint2* __restrict__ epk,
        const float* __restrict__ bias, int NN, int NNpad) {
    int slice = (NSL > 1) ? (int)(blockIdx.x % NSL) : 0;
    int nb = (NSL > 1) ? (int)(blockIdx.x / NSL) : (int)blockIdx.x;
    int wv = threadIdx.x >> 6;
    int wid = nb * 4 + wv;
    int lane = threadIdx.x & 63;
    if (wid >= NNpad) return;
    int c0 = slice * 128 + lane * 2;
    ushort* op = outb + (size_t)wid * LD + c0;
    if (wid >= NN) {  // zero pad rows (this slice's 256B)
        __builtin_nontemporal_store(0u, (uint*)op);
        return;
    }
    const ushort* Hc = H + c0;
    float a0 = 0.0f, a1 = 0.0f;
    {   // self-loop term
        float di = dinv[wid];
        float sw = di * di;
        uint u = *(const uint*)(Hc + (size_t)wid * LD);
        fma2(u, sw, a0, a1);
    }
    int e = offs[wid];
    int end = e + deg[wid];
    for (; e + 16 <= end; e += 16) agg_step<16, LD>(Hc, epk, e, a0, a1);
    if (e + 8 <= end) { agg_step<8, LD>(Hc, epk, e, a0, a1); e += 8; }
    if (e + 4 <= end) { agg_step<4, LD>(Hc, epk, e, a0, a1); e += 4; }
    if (e + 2 <= end) { agg_step<2, LD>(Hc, epk, e, a0, a1); e += 2; }
    if (e < end) agg_step<1, LD>(Hc, epk, e, a0, a1);
    if (BR) {
        a0 = fmaxf(a0 + bias[c0], 0.0f);
        a1 = fmaxf(a1 + bias[c0 + 1], 0.0f);
    }
    uint w = (uint)f2bf(a0) | ((uint)f2bf(a1) << 16);
    __builtin_nontemporal_store(w, (uint*)op);
}

// ---------------- agg1: first-layer aggregation exploiting prototype rows ----------------
// ~75% of srcs are one of 3 prototype rows -> their contribution is
// nf_t * (sum of norms). Edge list is class-segmented per dst: [0,d3) type-3
// (dense branch-free gathers), [d3,deg) proto (stream norms only).

template <int UNB>
__device__ __forceinline__ void proto_step(const uint2* __restrict__ epk, int e,
                                           float& s0, float& s1, float& s2) {
    uint2 q[UNB];
#pragma unroll
    for (int i = 0; i < UNB; ++i) q[i] = ldnt_u2(epk + e + i);
#pragma unroll
    for (int i = 0; i < UNB; ++i) {
        int t = (int)(q[i].x >> 30);
        float w = __uint_as_float(q[i].y);
        s0 += (t == 0) ? w : 0.f;
        s1 += (t == 1) ? w : 0.f;
        s2 += (t == 2) ? w : 0.f;
    }
}

__global__ __launch_bounds__(256) void k_agg1(
        const ushort* __restrict__ H, const float* __restrict__ nf,
        ushort* __restrict__ outb,
        const float* __restrict__ dinv, const int* __restrict__ offs,
        const int* __restrict__ degT, const int* __restrict__ cnt3,
        const uint2* __restrict__ epk, int NN, int NNpad) {
    int wid = (int)((blockIdx.x * blockDim.x + threadIdx.x) >> 6);
    int lane = threadIdx.x & 63;
    if (wid >= NNpad) return;
    int c0 = lane * 2;
    ushort* op = outb + (size_t)wid * 128 + c0;
    if (wid >= NN) {
        __builtin_nontemporal_store(0u, (uint*)op);
        return;
    }
    const ushort* Hc = H + c0;
    float a0 = 0.0f, a1 = 0.0f;
    {   // self-loop term (xb holds bf16 features for ALL node types)
        float di = dinv[wid];
        float sw = di * di;
        uint u = *(const uint*)(Hc + (size_t)wid * 128);
        fma2(u, sw, a0, a1);
    }
    int beg = offs[wid];
    int d3 = cnt3[wid];
    int dT = degT[wid];
    // segment A: type-3 srcs -> gather (dense, full MLP)
    int e = beg, endA = beg + d3;
    for (; e + 8 <= endA; e += 8) agg_step<8, 128>(Hc, epk, e, a0, a1);
    if (e + 4 <= endA) { agg_step<4, 128>(Hc, epk, e, a0, a1); e += 4; }
    if (e + 2 <= endA) { agg_step<2, 128>(Hc, epk, e, a0, a1); e += 2; }
    if (e < endA) agg_step<1, 128>(Hc, epk, e, a0, a1);
    // segment B: proto srcs -> per-type norm sums (no gathers)
    float s0 = 0.f, s1 = 0.f, s2 = 0.f;
    e = endA;
    int endB = beg + dT;
    for (; e + 8 <= endB; e += 8) proto_step<8>(epk, e, s0, s1, s2);
    if (e + 4 <= endB) { proto_step<4>(epk, e, s0, s1, s2); e += 4; }
    if (e + 2 <= endB) { proto_step<2>(epk, e, s0, s1, s2); e += 2; }
    if (e < endB) proto_step<1>(epk, e, s0, s1, s2);
    // fold prototype contributions (bf16-roundtripped to match xb rows)
    if (c0 < 100) {
        float p00 = bf2f(f2bf(nf[c0]));
        float p01 = bf2f(f2bf(nf[c0 + 1]));
        float p10 = bf2f(f2bf(nf[100 + c0]));
        float p11 = bf2f(f2bf(nf[100 + c0 + 1]));
        float p20 = bf2f(f2bf(nf[200 + c0]));
        float p21 = bf2f(f2bf(nf[200 + c0 + 1]));
        a0 += s0 * p00 + s1 * p10 + s2 * p20;
        a1 += s0 * p01 + s1 * p11 + s2 * p21;
    }
    uint w = (uint)f2bf(a0) | ((uint)f2bf(a1) << 16);
    __builtin_nontemporal_store(w, (uint*)op);
}

// ---------------- MFMA GEMM: A bf16 single plane, W hi/lo split (2-term) ----------------
// Block tile 128x128, 4 waves (64x64). KB=64 K-step: two 32-col LDS panels per
// barrier (each panel keeps the proven [row][32] layout / 64B read stride),
// 64 MFMA per sync instead of 16 — halves barrier-drain count. LDS 48KB;
// occupancy already VGPR-capped at ~3 waves/SIMD so the LDS bump is free.
// OUT: 1 = bf16 store, 2 = fused per-group row reduction into gsum[4][Nc].

template <bool BR, int OUT, int KB>
__global__ __launch_bounds__(256) void k_gemm(
        const ushort* __restrict__ A,
        const ushort* __restrict__ Bh, const ushort* __restrict__ Bl,
        const float* __restrict__ bias,
        ushort* __restrict__ Cb,
        int Nc, int K, int tNb,
        const int* __restrict__ gid, float* __restrict__ gsum, int NN) {
    constexpr int NP = KB / 32;  // panels per K-step
    __shared__ union {
        ushort st[3][128 * KB];
        float epi[64 * 132];
    } sm;
    __shared__ int gcode[64];
    int bm = blockIdx.x / tNb, bn = blockIdx.x % tNb;
    int m0 = bm * 128, n0 = bn * 128;
    int wv = threadIdx.x >> 6, lane = threadIdx.x & 63;
    int l15 = lane & 15, quad = lane >> 4;
    const ushort* gsrc;
    ushort* ldst;
    int ng;
    if (wv == 0)      { gsrc = A  + (size_t)m0 * K;        ldst = sm.st[0];        ng = 4; }
    else if (wv == 1) { gsrc = A  + (size_t)(m0 + 64) * K; ldst = sm.st[0] + 2048; ng = 4; }
    else if (wv == 2) { gsrc = Bh + (size_t)n0 * K;        ldst = sm.st[1];        ng = 8; }
    else              { gsrc = Bl + (size_t)n0 * K;        ldst = sm.st[2];        ng = 8; }
    const ushort* gBase = gsrc + (size_t)(lane >> 2) * K + (lane & 3) * 8;
    int wm = (wv >> 1) * 64, wn = (wv & 1) * 64;
    const ushort* sA_ = sm.st[0];
    const ushort* sBh_ = sm.st[1];
    const ushort* sBl_ = sm.st[2];
    f32x4 acc[4][4] = {};
    for (int k0 = 0; k0 < K; k0 += KB) {
#pragma unroll
        for (int p = 0; p < NP; ++p)
            for (int i = 0; i < ng; ++i)
                gll(gBase + (size_t)(16 * i) * K + k0 + p * 32, ldst + p * 4096 + i * 512);
        __syncthreads();
#pragma unroll
        for (int p = 0; p < NP; ++p) {
            bf16x8 Af[4], Bfh[4], Bfl[4];
#pragma unroll
            for (int i = 0; i < 4; ++i) {
                int ra = p * 4096 + (wm + 16 * i + l15) * 32 + quad * 8;
                int rb = p * 4096 + (wn + 16 * i + l15) * 32 + quad * 8;
                Af[i]  = *(const bf16x8*)(sA_ + ra);
                Bfh[i] = *(const bf16x8*)(sBh_ + rb);
                Bfl[i] = *(const bf16x8*)(sBl_ + rb);
            }
#pragma unroll
            for (int mi = 0; mi < 4; ++mi)
#pragma unroll
                for (int ni = 0; ni < 4; ++ni) {
                    acc[mi][ni] = __builtin_amdgcn_mfma_f32_16x16x32_bf16(Af[mi], Bfh[ni], acc[mi][ni], 0, 0, 0);
                    acc[mi][ni] = __builtin_amdgcn_mfma_f32_16x16x32_bf16(Af[mi], Bfl[ni], acc[mi][ni], 0, 0, 0);
                }
        }
        __syncthreads();
    }
    float bia[4] = {0.f, 0.f, 0.f, 0.f};
    if (BR) {
#pragma unroll
        for (int ni = 0; ni < 4; ++ni) {
            int col = n0 + wn + 16 * ni + l15;
            if (col < Nc) bia[ni] = bias[col];
        }
    }
    float* epi = sm.epi;
    int t = threadIdx.x;
    float s0 = 0.f, s1 = 0.f, s2 = 0.f, s3 = 0.f;  // OUT==2 per-group sums
    int colR = t & 127, rg = t >> 7;
    for (int half = 0; half < 2; ++half) {
        if ((wv >> 1) == half) {
#pragma unroll
            for (int mi = 0; mi < 4; ++mi)
#pragma unroll
                for (int r = 0; r < 4; ++r) {
                    int rl = mi * 16 + quad * 4 + r;
#pragma unroll
                    for (int ni = 0; ni < 4; ++ni) {
                        float v = acc[mi][ni][r];
                        if (BR) v = fmaxf(v + bia[ni], 0.0f);
                        epi[rl * 132 + wn + ni * 16 + l15] = v;
                    }
                }
        }
        if (OUT == 2 && t < 64) {
            int grow = m0 + half * 64 + t;
            gcode[t] = (grow < NN) ? gid[grow] : -1;
        }
        __syncthreads();
        if (OUT == 2) {
#pragma unroll 4
            for (int r = 0; r < 32; ++r) {
                int row = rg * 32 + r;
                int g = gcode[row];
                float v = epi[row * 132 + colR];
                s0 += (g == 0) ? v : 0.f;
                s1 += (g == 1) ? v : 0.f;
                s2 += (g == 2) ? v : 0.f;
                s3 += (g == 3) ? v : 0.f;
            }
        } else {
#pragma unroll
            for (int j = 0; j < 16; ++j) {
                int e = (j * 256 + t) * 2;
                int rl = e >> 7, cl = e & 127;
                int grow = m0 + half * 64 + rl;
                int gcol = n0 + cl;
                float v0 = epi[rl * 132 + cl];
                float v1 = epi[rl * 132 + cl + 1];
                *(uint*)&Cb[(size_t)grow * Nc + gcol] = (uint)f2bf(v0) | ((uint)f2bf(v1) << 16);
            }
        }
        __syncthreads();
    }
    if (OUT == 2) {
        if (rg == 1) {
            epi[colR * 4 + 0] = s0; epi[colR * 4 + 1] = s1;
            epi[colR * 4 + 2] = s2; epi[colR * 4 + 3] = s3;
        }
        __syncthreads();
        if (rg == 0) {
            s0 += epi[colR * 4 + 0]; s1 += epi[colR * 4 + 1];
            s2 += epi[colR * 4 + 2]; s3 += epi[colR * 4 + 3];
            int gcol = n0 + colR;
            if (gcol < Nc) {
                atomicAdd(&gsum[0 * Nc + gcol], s0);
                atomicAdd(&gsum[1 * Nc + gcol], s1);
                atomicAdd(&gsum[2 * Nc + gcol], s2);
                atomicAdd(&gsum[3 * Nc + gcol], s3);
            }
        }
    }
}

// ---------------- final: divide by precomputed group counts ----------------

__global__ void k_final(const float* __restrict__ gsum, const int* __restrict__ gcnt,
                        float* __restrict__ out) {
    int j = blockIdx.x * blockDim.x + threadIdx.x;
    if (j >= 800) return;
    int c = gcnt[j / 200];
    out[j] = (c > 0) ? gsum[j] / (float)c : 0.0f;
}

// ---------------- launch ----------------

extern "C" void kernel_launch(void* const* d_in, const int* in_sizes, int n_in,
                              void* d_out, int out_size, void* d_ws, size_t ws_size,
                              hipStream_t stream) {
    const float* x  = (const float*)d_in[0];
    const float* nf = (const float*)d_in[1];
    const int* ei   = (const int*)d_in[2];
    const float* W1 = (const float*)d_in[3];
    const float* b1 = (const float*)d_in[4];
    const float* W2 = (const float*)d_in[5];
    const float* b2 = (const float*)d_in[6];
    const float* W3 = (const float*)d_in[7];
    const float* b3 = (const float*)d_in[8];
    const float* W4 = (const float*)d_in[9];
    const float* b4 = (const float*)d_in[10];
    float* out = (float*)d_out;

    const int NN = in_sizes[0] / 100;  // 50000
    const int E  = in_sizes[2] / 2;    // 800000
    const int MPAD = ((NN + 127) / 128) * 128;  // 50048
    const int NB = (NN + 255) / 256;   // scan blocks (196 <= 256)
    const int PB = (NN + 3) / 4;       // prep blocks
    const int EB = (E + 255) / 256;    // deg/fill blocks
    const int TB = 1024;               // weight-split blocks
    const int* src = ei;
    const int* dst = ei + E;

    char* p = (char*)d_ws;
    auto alloc = [&](size_t bytes) -> char* {
        char* r = p;
        p += (bytes + 255) & ~(size_t)255;
        return r;
    };
    char* zz = p;
    int*   cnt3 = (int*)alloc((size_t)NN * 4);
    int*   cntP = (int*)alloc((size_t)NN * 4);
    float* gsum = (float*)alloc(800 * 4);
    int*   gcnt = (int*)alloc(256);
    size_t zz_bytes = (size_t)(p - zz);
    int*   degT = (int*)alloc((size_t)NN * 4);
    int*   slot = (int*)alloc((size_t)E * 4);
    float* dinv = (float*)alloc((size_t)NN * 4);
    int*   offs = (int*)alloc((size_t)NN * 4);   // block-local prefix (scanA)
    int*   goffs = (int*)alloc((size_t)NN * 4);  // global prefix (fill)
    int*   bsum = (int*)alloc(1024);
    int*   gid  = (int*)alloc((size_t)NN * 4);
    unsigned char* gidb = (unsigned char*)alloc((size_t)NN);
    uint2* epk  = (uint2*)alloc((size_t)E * 8);
    ushort* WT1h = (ushort*)alloc((size_t)512 * 128 * 2);
    ushort* WT1l = (ushort*)alloc((size_t)512 * 128 * 2);
    ushort* WT2h = (ushort*)alloc((size_t)256 * 512 * 2);
    ushort* WT2l = (ushort*)alloc((size_t)256 * 512 * 2);
    ushort* WT3h = (ushort*)alloc((size_t)128 * 256 * 2);
    ushort* WT3l = (ushort*)alloc((size_t)128 * 256 * 2);
    ushort* WT4h = (ushort*)alloc((size_t)256 * 128 * 2);
    ushort* WT4l = (ushort*)alloc((size_t)256 * 128 * 2);
    ushort* xb = (ushort*)alloc((size_t)NN * 128 * 2);
    ushort* P1 = (ushort*)alloc((size_t)MPAD * 128 * 2);
    ushort* H1 = (ushort*)alloc((size_t)MPAD * 512 * 2);
    ushort* T2 = (ushort*)alloc((size_t)MPAD * 256 * 2);
    ushort* H2 = (ushort*)alloc((size_t)MPAD * 256 * 2);
    ushort* T3 = (ushort*)alloc((size_t)MPAD * 128 * 2);
    ushort* H3 = (ushort*)alloc((size_t)MPAD * 128 * 2);
    ushort* P4 = (ushort*)alloc((size_t)MPAD * 128 * 2);

    hipMemsetAsync(zz, 0, zz_bytes, stream);

    k_prep<<<PB, 256, 0, stream>>>((const uint*)x, (const uint*)nf, xb, gid, gidb, NN);
    k_deg<<<EB, 256, 0, stream>>>(src, dst, E, gidb, cnt3, cntP, slot);
    k_wsplit<<<TB, 256, 0, stream>>>(W1, W2, W3, W4,
        WT1h, WT1l, WT2h, WT2l, WT3h, WT3l, WT4h, WT4l);
    k_scanA<<<NB, 256, 0, stream>>>(cnt3, cntP, degT, offs, bsum, dinv, gid, gcnt, NN);
    k_fill<<<EB, 256, 0, stream>>>(src, dst, slot, cnt3, E, dinv, offs, bsum, epk, NN, NB, goffs);

    int aggBlocks = MPAD / 4;  // one wave per node (per slice)
    int mB = MPAD / 128;

    // P1 = agg(xb) -> bf16 [MPAD,128]; prototype shortcut (gather only type-3 srcs)
    k_agg1<<<aggBlocks, 256, 0, stream>>>(xb, nf, P1, dinv, goffs, degT, cnt3, epk, NN, MPAD);
    // H1 = relu(P1 @ W1 + b1) -> bf16 [MPAD,512]
    k_gemm<true, 1, 64><<<mB * 4, 256, 0, stream>>>(P1, WT1h, WT1l, b1, H1, 512, 128, 4, nullptr, nullptr, 0);
    // T2 = H1 @ W2 -> bf16 [MPAD,256]
    k_gemm<false, 1, 64><<<mB * 2, 256, 0, stream>>>(H1, WT2h, WT2l, nullptr, T2, 256, 512, 2, nullptr, nullptr, 0);
    // H2 = relu(agg(T2) + b2) -> bf16 [MPAD,256], 2 XCD-pinned 128-col slices
    k_aggs<256, 2, true><<<aggBlocks * 2, 256, 0, stream>>>(T2, H2, dinv, goffs, degT, epk, b2, NN, MPAD);
    // T3 = H2 @ W3 -> bf16 [MPAD,128]
    k_gemm<false, 1, 64><<<mB * 1, 256, 0, stream>>>(H2, WT3h, WT3l, nullptr, T3, 128, 256, 1, nullptr, nullptr, 0);
    // H3 = relu(agg(T3) + b3) -> bf16 [MPAD,128]
    k_aggs<128, 1, true><<<aggBlocks, 256, 0, stream>>>(T3, H3, dinv, goffs, degT, epk, b3, NN, MPAD);
    // P4 = agg(H3) -> bf16 [MPAD,128]
    k_aggs<128, 1, false><<<aggBlocks, 256, 0, stream>>>(H3, P4, dinv, goffs, degT, epk, nullptr, NN, MPAD);
    // relu(P4 @ W4 + b4) -> per-group reduction into gsum (no H4 tensor)
    k_gemm<true, 2, 64><<<mB * 2, 256, 0, stream>>>(P4, WT4h, WT4l, b4, nullptr, 200, 128, 2, gid, gsum, NN);

    k_final<<<4, 256, 0, stream>>>(gsum, gcnt, out);
}

// Round 8
// 422.586 us; speedup vs baseline: 1.0319x; 1.0319x over previous
//
#include <hip/hip_runtime.h>
#include <stdint.h>

typedef __attribute__((ext_vector_type(8))) short bf16x8;
typedef __attribute__((ext_vector_type(4))) float f32x4;

__device__ __forceinline__ float bf2f(ushort h) {
    union { uint u; float f; } v; v.u = ((uint)h) << 16; return v.f;
}
__device__ __forceinline__ ushort f2bf(float f) {
    union { float f; uint u; } v; v.f = f;
    uint u = v.u;
    return (ushort)((u + 0x7fffu + ((u >> 16) & 1u)) >> 16);
}

// async global->LDS, 16B per lane; LDS dest = wave-uniform base + lane*16
__device__ __forceinline__ void gll(const ushort* g, ushort* l) {
    __builtin_amdgcn_global_load_lds(
        (const __attribute__((address_space(1))) void*)g,
        (__attribute__((address_space(3))) void*)l, 16, 0, 0);
}

// ---------------- prep: classify nodes + x->bf16 (padded to 128 cols) ----------------

__global__ void k_prep(const uint* __restrict__ xu, const uint* __restrict__ nfu,
                       ushort* __restrict__ xb, int* __restrict__ gid,
                       unsigned char* __restrict__ gidb, int NN) {
    int wid = blockIdx.x * 4 + (threadIdx.x >> 6);
    int lane = threadIdx.x & 63;
    if (wid >= NN) return;
    int c0 = lane * 2;
    uint w = 0u;
    int m0 = 1, m1 = 1, m2 = 1;
    if (c0 < 100) {
        uint2 xv = *(const uint2*)&xu[(size_t)wid * 100 + c0];
        uint2 a = *(const uint2*)&nfu[c0];
        uint2 bb = *(const uint2*)&nfu[100 + c0];
        uint2 c = *(const uint2*)&nfu[200 + c0];
        m0 = (xv.x == a.x) & (xv.y == a.y);
        m1 = (xv.x == bb.x) & (xv.y == bb.y);
        m2 = (xv.x == c.x) & (xv.y == c.y);
        w = (uint)f2bf(__uint_as_float(xv.x)) | ((uint)f2bf(__uint_as_float(xv.y)) << 16);
    }
    int e0 = __all(m0), e1 = __all(m1), e2 = __all(m2);
    *(uint*)&xb[(size_t)wid * 128 + c0] = w;
    if (lane == 0) {
        // group id for the output reduction: 0/3/1/2 mapping (unchanged)
        gid[wid] = e0 ? 0 : (e1 ? 3 : (e2 ? 1 : 2));
        // prototype id for agg1: 0,1,2 = nf row index, 3 = random features
        gidb[wid] = (unsigned char)(e0 ? 0 : (e1 ? 1 : (e2 ? 2 : 3)));
    }
}

// ---------------- deg: per-dst counters split by src class (type3 | proto) ----------------
// slot[e] = within-class slot | (ptype<<28). Type-3 edges get slots [0,d3),
// proto edges [d3,deg) -> agg1 runs a dense gather segment + a norm-only segment.

__global__ void k_deg(const int* __restrict__ src, const int* __restrict__ dst, int E,
                      const unsigned char* __restrict__ gidb,
                      int* __restrict__ cnt3, int* __restrict__ cntP,
                      int* __restrict__ slot) {
    int e = blockIdx.x * 256 + threadIdx.x;
    if (e >= E) return;
    int d = dst[e];
    int t = gidb[src[e]];  // 50KB table, L1/L2-hot
    int s;
    if (t == 3) s = atomicAdd(&cnt3[d], 1);
    else        s = atomicAdd(&cntP[d], 1);
    slot[e] = s | (t << 28);
}

// ---------------- wsplit: W -> bf16 hi/lo transposed planes ----------------

__device__ __forceinline__ void tr2_one(const float* __restrict__ W,
                                        ushort* __restrict__ WTh, ushort* __restrict__ WTl,
                                        int K, int Nc, int KP, int idx) {
    int n = idx / KP, k = idx % KP;
    float w = (n < Nc && k < K) ? W[(size_t)k * Nc + n] : 0.0f;
    ushort hi = f2bf(w);
    ushort lo = f2bf(w - bf2f(hi));
    WTh[idx] = hi;
    WTl[idx] = lo;
}

__global__ void k_wsplit(const float* __restrict__ W1, const float* __restrict__ W2,
                         const float* __restrict__ W3, const float* __restrict__ W4,
                         ushort* __restrict__ WT1h, ushort* __restrict__ WT1l,
                         ushort* __restrict__ WT2h, ushort* __restrict__ WT2l,
                         ushort* __restrict__ WT3h, ushort* __restrict__ WT3l,
                         ushort* __restrict__ WT4h, ushort* __restrict__ WT4l) {
    int idx = blockIdx.x * 256 + threadIdx.x;
    if (idx < 65536) tr2_one(W1, WT1h, WT1l, 100, 512, 128, idx);
    else if (idx < 196608) tr2_one(W2, WT2h, WT2l, 512, 256, 512, idx - 65536);
    else if (idx < 229376) tr2_one(W3, WT3h, WT3l, 256, 128, 256, idx - 196608);
    else if (idx < 262144) tr2_one(W4, WT4h, WT4l, 128, 200, 128, idx - 229376);
}

// ---------------- scanA: block-local prefix + dinv + group counts ----------------

__global__ void k_scanA(const int* __restrict__ cnt3, const int* __restrict__ cntP,
                        int* __restrict__ degT, int* __restrict__ offs,
                        int* __restrict__ bsum, float* __restrict__ dinv,
                        const int* __restrict__ gid, int* __restrict__ gcnt, int NN) {
    __shared__ int lds[256];
    __shared__ int cnt4[4];
    int t = threadIdx.x;
    if (t < 4) cnt4[t] = 0;
    int i = blockIdx.x * 256 + t;
    int v = (i < NN) ? (cnt3[i] + cntP[i]) : 0;
    if (i < NN) {
        degT[i] = v;
        dinv[i] = 1.0f / sqrtf((float)(v + 1));  // +1 self loop
    }
    lds[t] = v;
    __syncthreads();
    if (i < NN) atomicAdd(&cnt4[gid[i]], 1);
    for (int d = 1; d < 256; d <<= 1) {
        int u = (t >= d) ? lds[t - d] : 0;
        __syncthreads();
        lds[t] += u;
        __syncthreads();
    }
    if (i < NN) offs[i] = lds[t] - v;  // block-local exclusive
    if (t == 255) bsum[blockIdx.x] = lds[255];
    __syncthreads();
    if (t < 4 && cnt4[t]) atomicAdd(&gcnt[t], cnt4[t]);
}

// ---------------- fill: atomic-free placement, class-segmented slots ----------------

__global__ void k_fill(const int* __restrict__ src, const int* __restrict__ dst,
                       const int* __restrict__ slot, const int* __restrict__ cnt3, int E,
                       const float* __restrict__ dinv, const int* __restrict__ offs,
                       const int* __restrict__ bsum,
                       uint2* __restrict__ epk, int NN, int NB,
                       int* __restrict__ goffs) {
    __shared__ int sex[256];
    int t = threadIdx.x;
    int v = (t < NB) ? bsum[t] : 0;
    sex[t] = v;
    __syncthreads();
    for (int d = 1; d < 256; d <<= 1) {
        int u = (t >= d) ? sex[t - d] : 0;
        __syncthreads();
        sex[t] += u;
        __syncthreads();
    }
    int incl = sex[t];
    __syncthreads();
    sex[t] = incl - v;  // exclusive prefix of bsum
    __syncthreads();
    int i = blockIdx.x * 256 + t;
    if (i < NN) goffs[i] = offs[i] + sex[i >> 8];
    if (i >= E) return;
    int s = src[i], d = dst[i];
    int sl = slot[i];
    int ty = sl >> 28;
    int sp = sl & 0x0FFFFFFF;
    int base = offs[d] + sex[d >> 8];
    int p = base + ((ty == 3) ? sp : (cnt3[d] + sp));
    epk[p] = make_uint2((uint)s | ((uint)ty << 30), __float_as_uint(dinv[s] * dinv[d]));
}

// ---------------- aggregation ----------------
// r2-r5 findings: all D=256 agg variants (fetch 160-188MB, 5 different issue
// structures) run at ~59.8us; D=128 at ~half => time ~ total 64B lines
// requested (~request-byte wall at ~7 TB/s delivered). Not HBM-BW, not L2-BW,
// not VALU. Aggs are at their structural floor at bf16 row width; leave alone.
// epk.x carries src | (ptype<<30); mask with 0x3FFFFFFF when gathering.

__device__ __forceinline__ uint2 ldnt_u2(const uint2* p) {
    union { unsigned long long ll; uint2 v; } r;
    r.ll = __builtin_nontemporal_load((const unsigned long long*)p);
    return r.v;
}

__device__ __forceinline__ void fma2(uint u, float w, float& a0, float& a1) {
    union { uint u; float f; } lo, hi;
    lo.u = u << 16;           // bf16 low element -> f32
    hi.u = u & 0xffff0000u;   // bf16 high element -> f32
    a0 = fmaf(w, lo.f, a0);
    a1 = fmaf(w, hi.f, a1);
}

template <int UN, int LD>
__device__ __forceinline__ void agg_step(const ushort* __restrict__ Hc,
                                         const uint2* __restrict__ epk, int e,
                                         float& a0, float& a1) {
    uint2 q[UN];
#pragma unroll
    for (int i = 0; i < UN; ++i) q[i] = ldnt_u2(epk + e + i);
    uint u[UN];
#pragma unroll
    for (int i = 0; i < UN; ++i)
        u[i] = *(const uint*)(Hc + (size_t)(q[i].x & 0x3FFFFFFFu) * LD);
#pragma unroll
    for (int i = 0; i < UN; ++i) fma2(u[i], __uint_as_float(q[i].y), a0, a1);
}

// One wave per node per 128-col slice; slice = blockIdx % NSL (NSL | 8) pins
// slices to XCD classes (r4: cuts fetch 187->160MB, time-neutral; kept).
template <int LD, int NSL, bool BR>
__global__ __launch_bounds__(256) void k_aggs(
        const ushort* __restrict__ H, ushort* __restrict__ outb,
        const float* __restrict__ dinv, const int* __restrict__ offs,
        const int* __restrict__ deg, const uint2* __restrict__ epk,
        const float* __restrict__ bias, int NN, int NNpad) {
    int slice = (NSL > 1) ? (int)(blockIdx.x % NSL) : 0;
    int nb = (NSL > 1) ? (int)(blockIdx.x / NSL) : (int)blockIdx.x;
    int wv = threadIdx.x >> 6;
    int wid = nb * 4 + wv;
    int lane = threadIdx.x & 63;
    if (wid >= NNpad) return;
    int c0 = slice * 128 + lane * 2;
    ushort* op = outb + (size_t)wid * LD + c0;
    if (wid >= NN) {  // zero pad rows (this slice's 256B)
        __builtin_nontemporal_store(0u, (uint*)op);
        return;
    }
    const ushort* Hc = H + c0;
    float a0 = 0.0f, a1 = 0.0f;
    {   // self-loop term
        float di = dinv[wid];
        float sw = di * di;
        uint u = *(const uint*)(Hc + (size_t)wid * LD);
        fma2(u, sw, a0, a1);
    }
    int e = offs[wid];
    int end = e + deg[wid];
    for (; e + 16 <= end; e += 16) agg_step<16, LD>(Hc, epk, e, a0, a1);
    if (e + 8 <= end) { agg_step<8, LD>(Hc, epk, e, a0, a1); e += 8; }
    if (e + 4 <= end) { agg_step<4, LD>(Hc, epk, e, a0, a1); e += 4; }
    if (e + 2 <= end) { agg_step<2, LD>(Hc, epk, e, a0, a1); e += 2; }
    if (e < end) agg_step<1, LD>(Hc, epk, e, a0, a1);
    if (BR) {
        a0 = fmaxf(a0 + bias[c0], 0.0f);
        a1 = fmaxf(a1 + bias[c0 + 1], 0.0f);
    }
    uint w = (uint)f2bf(a0) | ((uint)f2bf(a1) << 16);
    __builtin_nontemporal_store(w, (uint*)op);
}

// ---------------- agg1: first-layer aggregation exploiting prototype rows ----------------
// ~75% of srcs are one of 3 prototype rows -> their contribution is
// nf_t * (sum of norms). Edge list is class-segmented per dst: [0,d3) type-3
// (dense branch-free gathers), [d3,deg) proto (stream norms only).

template <int UNB>
__device__ __forceinline__ void proto_step(const uint2* __restrict__ epk, int e,
                                           float& s0, float& s1, float& s2) {
    uint2 q[UNB];
#pragma unroll
    for (int i = 0; i < UNB; ++i) q[i] = ldnt_u2(epk + e + i);
#pragma unroll
    for (int i = 0; i < UNB; ++i) {
        int t = (int)(q[i].x >> 30);
        float w = __uint_as_float(q[i].y);
        s0 += (t == 0) ? w : 0.f;
        s1 += (t == 1) ? w : 0.f;
        s2 += (t == 2) ? w : 0.f;
    }
}

__global__ __launch_bounds__(256) void k_agg1(
        const ushort* __restrict__ H, const float* __restrict__ nf,
        ushort* __restrict__ outb,
        const float* __restrict__ dinv, const int* __restrict__ offs,
        const int* __restrict__ degT, const int* __restrict__ cnt3,
        const uint2* __restrict__ epk, int NN, int NNpad) {
    int wid = (int)((blockIdx.x * blockDim.x + threadIdx.x) >> 6);
    int lane = threadIdx.x & 63;
    if (wid >= NNpad) return;
    int c0 = lane * 2;
    ushort* op = outb + (size_t)wid * 128 + c0;
    if (wid >= NN) {
        __builtin_nontemporal_store(0u, (uint*)op);
        return;
    }
    const ushort* Hc = H + c0;
    float a0 = 0.0f, a1 = 0.0f;
    {   // self-loop term (xb holds bf16 features for ALL node types)
        float di = dinv[wid];
        float sw = di * di;
        uint u = *(const uint*)(Hc + (size_t)wid * 128);
        fma2(u, sw, a0, a1);
    }
    int beg = offs[wid];
    int d3 = cnt3[wid];
    int dT = degT[wid];
    // segment A: type-3 srcs -> gather (dense, full MLP)
    int e = beg, endA = beg + d3;
    for (; e + 8 <= endA; e += 8) agg_step<8, 128>(Hc, epk, e, a0, a1);
    if (e + 4 <= endA) { agg_step<4, 128>(Hc, epk, e, a0, a1); e += 4; }
    if (e + 2 <= endA) { agg_step<2, 128>(Hc, epk, e, a0, a1); e += 2; }
    if (e < endA) agg_step<1, 128>(Hc, epk, e, a0, a1);
    // segment B: proto srcs -> per-type norm sums (no gathers)
    float s0 = 0.f, s1 = 0.f, s2 = 0.f;
    e = endA;
    int endB = beg + dT;
    for (; e + 8 <= endB; e += 8) proto_step<8>(epk, e, s0, s1, s2);
    if (e + 4 <= endB) { proto_step<4>(epk, e, s0, s1, s2); e += 4; }
    if (e + 2 <= endB) { proto_step<2>(epk, e, s0, s1, s2); e += 2; }
    if (e < endB) proto_step<1>(epk, e, s0, s1, s2);
    // fold prototype contributions (bf16-roundtripped to match xb rows)
    if (c0 < 100) {
        float p00 = bf2f(f2bf(nf[c0]));
        float p01 = bf2f(f2bf(nf[c0 + 1]));
        float p10 = bf2f(f2bf(nf[100 + c0]));
        float p11 = bf2f(f2bf(nf[100 + c0 + 1]));
        float p20 = bf2f(f2bf(nf[200 + c0]));
        float p21 = bf2f(f2bf(nf[200 + c0 + 1]));
        a0 += s0 * p00 + s1 * p10 + s2 * p20;
        a1 += s0 * p01 + s1 * p11 + s2 * p21;
    }
    uint w = (uint)f2bf(a0) | ((uint)f2bf(a1) << 16);
    __builtin_nontemporal_store(w, (uint*)op);
}

// ---------------- MFMA GEMM: double-buffered staging with counted vmcnt (T3/T4) ----------------
// r7: BK=64 (more MFMA per barrier) was NEUTRAL -> not barrier-count-bound.
// Remaining suspect: __syncthreads' implicit vmcnt(0) drains the gll queue
// every K-step (the documented m97 stall). Fix per guide's verified template:
// 2 LDS buffers; issue next-tile gll BEFORE compute; s_waitcnt vmcnt(ng)
// (own outstanding prefetch stays in flight — never 0 in main loop); raw
// s_barrier + sched_barrier(0); MFMA; barrier. Waves wait wave-uniform counts
// (A-waves 4, B-waves 8). LDS 48KB -> 3 blocks/CU unchanged.

template <bool BR, int OUT>
__global__ __launch_bounds__(256) void k_gemm(
        const ushort* __restrict__ A,
        const ushort* __restrict__ Bh, const ushort* __restrict__ Bl,
        const float* __restrict__ bias,
        ushort* __restrict__ Cb,
        int Nc, int K, int tNb,
        const int* __restrict__ gid, float* __restrict__ gsum, int NN) {
    __shared__ union {
        ushort st[2][3][128 * 32];  // [dbuf][plane A/Bh/Bl][row*32 + col]
        float epi[64 * 132];
    } sm;
    __shared__ int gcode[64];
    int bm = blockIdx.x / tNb, bn = blockIdx.x % tNb;
    int m0 = bm * 128, n0 = bn * 128;
    int wv = threadIdx.x >> 6, lane = threadIdx.x & 63;
    int l15 = lane & 15, quad = lane >> 4;
    const ushort* gsrc;
    int plane, woff, ng;
    if (wv == 0)      { gsrc = A  + (size_t)m0 * K;        plane = 0; woff = 0;    ng = 4; }
    else if (wv == 1) { gsrc = A  + (size_t)(m0 + 64) * K; plane = 0; woff = 2048; ng = 4; }
    else if (wv == 2) { gsrc = Bh + (size_t)n0 * K;        plane = 1; woff = 0;    ng = 8; }
    else              { gsrc = Bl + (size_t)n0 * K;        plane = 2; woff = 0;    ng = 8; }
    const ushort* gBase = gsrc + (size_t)(lane >> 2) * K + (lane & 3) * 8;
    ushort* lBase = &sm.st[0][0][0] + plane * 4096 + woff;
    const ushort* sAll = &sm.st[0][0][0];
    int wm = (wv >> 1) * 64, wn = (wv & 1) * 64;
    f32x4 acc[4][4] = {};
    int nk = K >> 5;
    // prologue: stage K-step 0 into buffer 0
    for (int i = 0; i < ng; ++i)
        gll(gBase + (size_t)(16 * i) * K, lBase + i * 512);
    for (int k = 0; k < nk; ++k) {
        int cur = k & 1;
        if (k + 1 < nk) {
            // issue next tile into the other buffer; do NOT wait for it
            ushort* l2 = lBase + (cur ^ 1) * 12288;
            const ushort* g2 = gBase + (k + 1) * 32;
            for (int i = 0; i < ng; ++i)
                gll(g2 + (size_t)(16 * i) * K, l2 + i * 512);
            if (ng == 4) asm volatile("s_waitcnt vmcnt(4)" ::: "memory");
            else         asm volatile("s_waitcnt vmcnt(8)" ::: "memory");
        } else {
            asm volatile("s_waitcnt vmcnt(0)" ::: "memory");
        }
        __builtin_amdgcn_s_barrier();          // all waves' cur-buffer loads landed
        __builtin_amdgcn_sched_barrier(0);     // rule 18: pin reads below the wait
        const ushort* sA_  = sAll + cur * 12288;
        const ushort* sBh_ = sA_ + 4096;
        const ushort* sBl_ = sA_ + 8192;
        bf16x8 Af[4], Bfh[4], Bfl[4];
#pragma unroll
        for (int i = 0; i < 4; ++i) {
            int ra = (wm + 16 * i + l15) * 32 + quad * 8;
            int rb = (wn + 16 * i + l15) * 32 + quad * 8;
            Af[i]  = *(const bf16x8*)(sA_ + ra);
            Bfh[i] = *(const bf16x8*)(sBh_ + rb);
            Bfl[i] = *(const bf16x8*)(sBl_ + rb);
        }
#pragma unroll
        for (int mi = 0; mi < 4; ++mi)
#pragma unroll
            for (int ni = 0; ni < 4; ++ni) {
                acc[mi][ni] = __builtin_amdgcn_mfma_f32_16x16x32_bf16(Af[mi], Bfh[ni], acc[mi][ni], 0, 0, 0);
                acc[mi][ni] = __builtin_amdgcn_mfma_f32_16x16x32_bf16(Af[mi], Bfl[ni], acc[mi][ni], 0, 0, 0);
            }
        __builtin_amdgcn_s_barrier();          // all waves done reading cur buffer
    }
    __builtin_amdgcn_sched_barrier(0);
    float bia[4] = {0.f, 0.f, 0.f, 0.f};
    if (BR) {
#pragma unroll
        for (int ni = 0; ni < 4; ++ni) {
            int col = n0 + wn + 16 * ni + l15;
            if (col < Nc) bia[ni] = bias[col];
        }
    }
    float* epi = sm.epi;
    int t = threadIdx.x;
    float s0 = 0.f, s1 = 0.f, s2 = 0.f, s3 = 0.f;  // OUT==2 per-group sums
    int colR = t & 127, rg = t >> 7;
    for (int half = 0; half < 2; ++half) {
        if ((wv >> 1) == half) {
#pragma unroll
            for (int mi = 0; mi < 4; ++mi)
#pragma unroll
                for (int r = 0; r < 4; ++r) {
                    int rl = mi * 16 + quad * 4 + r;
#pragma unroll
                    for (int ni = 0; ni < 4; ++ni) {
                        float v = acc[mi][ni][r];
                        if (BR) v = fmaxf(v + bia[ni], 0.0f);
                        epi[rl * 132 + wn + ni * 16 + l15] = v;
                    }
                }
        }
        if (OUT == 2 && t < 64) {
            int grow = m0 + half * 64 + t;
            gcode[t] = (grow < NN) ? gid[grow] : -1;
        }
        __syncthreads();
        if (OUT == 2) {
#pragma unroll 4
            for (int r = 0; r < 32; ++r) {
                int row = rg * 32 + r;
                int g = gcode[row];
                float v = epi[row * 132 + colR];
                s0 += (g == 0) ? v : 0.f;
                s1 += (g == 1) ? v : 0.f;
                s2 += (g == 2) ? v : 0.f;
                s3 += (g == 3) ? v : 0.f;
            }
        } else {
#pragma unroll
            for (int j = 0; j < 16; ++j) {
                int e = (j * 256 + t) * 2;
                int rl = e >> 7, cl = e & 127;
                int grow = m0 + half * 64 + rl;
                int gcol = n0 + cl;
                float v0 = epi[rl * 132 + cl];
                float v1 = epi[rl * 132 + cl + 1];
                *(uint*)&Cb[(size_t)grow * Nc + gcol] = (uint)f2bf(v0) | ((uint)f2bf(v1) << 16);
            }
        }
        __syncthreads();
    }
    if (OUT == 2) {
        if (rg == 1) {
            epi[colR * 4 + 0] = s0; epi[colR * 4 + 1] = s1;
            epi[colR * 4 + 2] = s2; epi[colR * 4 + 3] = s3;
        }
        __syncthreads();
        if (rg == 0) {
            s0 += epi[colR * 4 + 0]; s1 += epi[colR * 4 + 1];
            s2 += epi[colR * 4 + 2]; s3 += epi[colR * 4 + 3];
            int gcol = n0 + colR;
            if (gcol < Nc) {
                atomicAdd(&gsum[0 * Nc + gcol], s0);
                atomicAdd(&gsum[1 * Nc + gcol], s1);
                atomicAdd(&gsum[2 * Nc + gcol], s2);
                atomicAdd(&gsum[3 * Nc + gcol], s3);
            }
        }
    }
}

// ---------------- final: divide by precomputed group counts ----------------

__global__ void k_final(const float* __restrict__ gsum, const int* __restrict__ gcnt,
                        float* __restrict__ out) {
    int j = blockIdx.x * blockDim.x + threadIdx.x;
    if (j >= 800) return;
    int c = gcnt[j / 200];
    out[j] = (c > 0) ? gsum[j] / (float)c : 0.0f;
}

// ---------------- launch ----------------

extern "C" void kernel_launch(void* const* d_in, const int* in_sizes, int n_in,
                              void* d_out, int out_size, void* d_ws, size_t ws_size,
                              hipStream_t stream) {
    const float* x  = (const float*)d_in[0];
    const float* nf = (const float*)d_in[1];
    const int* ei   = (const int*)d_in[2];
    const float* W1 = (const float*)d_in[3];
    const float* b1 = (const float*)d_in[4];
    const float* W2 = (const float*)d_in[5];
    const float* b2 = (const float*)d_in[6];
    const float* W3 = (const float*)d_in[7];
    const float* b3 = (const float*)d_in[8];
    const float* W4 = (const float*)d_in[9];
    const float* b4 = (const float*)d_in[10];
    float* out = (float*)d_out;

    const int NN = in_sizes[0] / 100;  // 50000
    const int E  = in_sizes[2] / 2;    // 800000
    const int MPAD = ((NN + 127) / 128) * 128;  // 50048
    const int NB = (NN + 255) / 256;   // scan blocks (196 <= 256)
    const int PB = (NN + 3) / 4;       // prep blocks
    const int EB = (E + 255) / 256;    // deg/fill blocks
    const int TB = 1024;               // weight-split blocks
    const int* src = ei;
    const int* dst = ei + E;

    char* p = (char*)d_ws;
    auto alloc = [&](size_t bytes) -> char* {
        char* r = p;
        p += (bytes + 255) & ~(size_t)255;
        return r;
    };
    char* zz = p;
    int*   cnt3 = (int*)alloc((size_t)NN * 4);
    int*   cntP = (int*)alloc((size_t)NN * 4);
    float* gsum = (float*)alloc(800 * 4);
    int*   gcnt = (int*)alloc(256);
    size_t zz_bytes = (size_t)(p - zz);
    int*   degT = (int*)alloc((size_t)NN * 4);
    int*   slot = (int*)alloc((size_t)E * 4);
    float* dinv = (float*)alloc((size_t)NN * 4);
    int*   offs = (int*)alloc((size_t)NN * 4);   // block-local prefix (scanA)
    int*   goffs = (int*)alloc((size_t)NN * 4);  // global prefix (fill)
    int*   bsum = (int*)alloc(1024);
    int*   gid  = (int*)alloc((size_t)NN * 4);
    unsigned char* gidb = (unsigned char*)alloc((size_t)NN);
    uint2* epk  = (uint2*)alloc((size_t)E * 8);
    ushort* WT1h = (ushort*)alloc((size_t)512 * 128 * 2);
    ushort* WT1l = (ushort*)alloc((size_t)512 * 128 * 2);
    ushort* WT2h = (ushort*)alloc((size_t)256 * 512 * 2);
    ushort* WT2l = (ushort*)alloc((size_t)256 * 512 * 2);
    ushort* WT3h = (ushort*)alloc((size_t)128 * 256 * 2);
    ushort* WT3l = (ushort*)alloc((size_t)128 * 256 * 2);
    ushort* WT4h = (ushort*)alloc((size_t)256 * 128 * 2);
    ushort* WT4l = (ushort*)alloc((size_t)256 * 128 * 2);
    ushort* xb = (ushort*)alloc((size_t)NN * 128 * 2);
    ushort* P1 = (ushort*)alloc((size_t)MPAD * 128 * 2);
    ushort* H1 = (ushort*)alloc((size_t)MPAD * 512 * 2);
    ushort* T2 = (ushort*)alloc((size_t)MPAD * 256 * 2);
    ushort* H2 = (ushort*)alloc((size_t)MPAD * 256 * 2);
    ushort* T3 = (ushort*)alloc((size_t)MPAD * 128 * 2);
    ushort* H3 = (ushort*)alloc((size_t)MPAD * 128 * 2);
    ushort* P4 = (ushort*)alloc((size_t)MPAD * 128 * 2);

    hipMemsetAsync(zz, 0, zz_bytes, stream);

    k_prep<<<PB, 256, 0, stream>>>((const uint*)x, (const uint*)nf, xb, gid, gidb, NN);
    k_deg<<<EB, 256, 0, stream>>>(src, dst, E, gidb, cnt3, cntP, slot);
    k_wsplit<<<TB, 256, 0, stream>>>(W1, W2, W3, W4,
        WT1h, WT1l, WT2h, WT2l, WT3h, WT3l, WT4h, WT4l);
    k_scanA<<<NB, 256, 0, stream>>>(cnt3, cntP, degT, offs, bsum, dinv, gid, gcnt, NN);
    k_fill<<<EB, 256, 0, stream>>>(src, dst, slot, cnt3, E, dinv, offs, bsum, epk, NN, NB, goffs);

    int aggBlocks = MPAD / 4;  // one wave per node (per slice)
    int mB = MPAD / 128;

    // P1 = agg(xb) -> bf16 [MPAD,128]; prototype shortcut (gather only type-3 srcs)
    k_agg1<<<aggBlocks, 256, 0, stream>>>(xb, nf, P1, dinv, goffs, degT, cnt3, epk, NN, MPAD);
    // H1 = relu(P1 @ W1 + b1) -> bf16 [MPAD,512]
    k_gemm<true, 1><<<mB * 4, 256, 0, stream>>>(P1, WT1h, WT1l, b1, H1, 512, 128, 4, nullptr, nullptr, 0);
    // T2 = H1 @ W2 -> bf16 [MPAD,256]
    k_gemm<false, 1><<<mB * 2, 256, 0, stream>>>(H1, WT2h, WT2l, nullptr, T2, 256, 512, 2, nullptr, nullptr, 0);
    // H2 = relu(agg(T2) + b2) -> bf16 [MPAD,256], 2 XCD-pinned 128-col slices
    k_aggs<256, 2, true><<<aggBlocks * 2, 256, 0, stream>>>(T2, H2, dinv, goffs, degT, epk, b2, NN, MPAD);
    // T3 = H2 @ W3 -> bf16 [MPAD,128]
    k_gemm<false, 1><<<mB * 1, 256, 0, stream>>>(H2, WT3h, WT3l, nullptr, T3, 128, 256, 1, nullptr, nullptr, 0);
    // H3 = relu(agg(T3) + b3) -> bf16 [MPAD,128]
    k_aggs<128, 1, true><<<aggBlocks, 256, 0, stream>>>(T3, H3, dinv, goffs, degT, epk, b3, NN, MPAD);
    // P4 = agg(H3) -> bf16 [MPAD,128]
    k_aggs<128, 1, false><<<aggBlocks, 256, 0, stream>>>(H3, P4, dinv, goffs, degT, epk, nullptr, NN, MPAD);
    // relu(P4 @ W4 + b4) -> per-group reduction into gsum (no H4 tensor)
    k_gemm<true, 2><<<mB * 2, 256, 0, stream>>>(P4, WT4h, WT4l, b4, nullptr, 200, 128, 2, gid, gsum, NN);

    k_final<<<4, 256, 0, stream>>>(gsum, gcnt, out);
}

// Round 9
// 422.027 us; speedup vs baseline: 1.0332x; 1.0013x over previous
//
#include <hip/hip_runtime.h>
#include <stdint.h>

typedef __attribute__((ext_vector_type(8))) short bf16x8;
typedef __attribute__((ext_vector_type(4))) float f32x4;

__device__ __forceinline__ float bf2f(ushort h) {
    union { uint u; float f; } v; v.u = ((uint)h) << 16; return v.f;
}
__device__ __forceinline__ ushort f2bf(float f) {
    union { float f; uint u; } v; v.f = f;
    uint u = v.u;
    return (ushort)((u + 0x7fffu + ((u >> 16) & 1u)) >> 16);
}

// async global->LDS, 16B per lane; LDS dest = wave-uniform base + lane*16
__device__ __forceinline__ void gll(const ushort* g, ushort* l) {
    __builtin_amdgcn_global_load_lds(
        (const __attribute__((address_space(1))) void*)g,
        (__attribute__((address_space(3))) void*)l, 16, 0, 0);
}

// ---------------- prep+wsplit merged: one dispatch, independent sections ----------------

__device__ __forceinline__ void tr2_one(const float* __restrict__ W,
                                        ushort* __restrict__ WTh, ushort* __restrict__ WTl,
                                        int K, int Nc, int KP, int idx) {
    int n = idx / KP, k = idx % KP;
    float w = (n < Nc && k < K) ? W[(size_t)k * Nc + n] : 0.0f;
    ushort hi = f2bf(w);
    ushort lo = f2bf(w - bf2f(hi));
    WTh[idx] = hi;
    WTl[idx] = lo;
}

__global__ void k_prepw(const uint* __restrict__ xu, const uint* __restrict__ nfu,
                        ushort* __restrict__ xb, int* __restrict__ gid,
                        unsigned char* __restrict__ gidb, int NN, int PB,
                        const float* __restrict__ W1, const float* __restrict__ W2,
                        const float* __restrict__ W3, const float* __restrict__ W4,
                        ushort* __restrict__ WT1h, ushort* __restrict__ WT1l,
                        ushort* __restrict__ WT2h, ushort* __restrict__ WT2l,
                        ushort* __restrict__ WT3h, ushort* __restrict__ WT3l,
                        ushort* __restrict__ WT4h, ushort* __restrict__ WT4l) {
    int b = blockIdx.x;
    if (b < PB) {
        int wid = b * 4 + (threadIdx.x >> 6);
        int lane = threadIdx.x & 63;
        if (wid >= NN) return;
        int c0 = lane * 2;
        uint w = 0u;
        int m0 = 1, m1 = 1, m2 = 1;
        if (c0 < 100) {
            uint2 xv = *(const uint2*)&xu[(size_t)wid * 100 + c0];
            uint2 a = *(const uint2*)&nfu[c0];
            uint2 bb = *(const uint2*)&nfu[100 + c0];
            uint2 c = *(const uint2*)&nfu[200 + c0];
            m0 = (xv.x == a.x) & (xv.y == a.y);
            m1 = (xv.x == bb.x) & (xv.y == bb.y);
            m2 = (xv.x == c.x) & (xv.y == c.y);
            w = (uint)f2bf(__uint_as_float(xv.x)) | ((uint)f2bf(__uint_as_float(xv.y)) << 16);
        }
        int e0 = __all(m0), e1 = __all(m1), e2 = __all(m2);
        *(uint*)&xb[(size_t)wid * 128 + c0] = w;
        if (lane == 0) {
            // group id for the output reduction: 0/3/1/2 mapping (unchanged)
            gid[wid] = e0 ? 0 : (e1 ? 3 : (e2 ? 1 : 2));
            // prototype id for agg1: 0,1,2 = nf row index, 3 = random features
            gidb[wid] = (unsigned char)(e0 ? 0 : (e1 ? 1 : (e2 ? 2 : 3)));
        }
    } else {
        int idx = (b - PB) * 256 + threadIdx.x;
        if (idx < 65536) tr2_one(W1, WT1h, WT1l, 100, 512, 128, idx);
        else if (idx < 196608) tr2_one(W2, WT2h, WT2l, 512, 256, 512, idx - 65536);
        else if (idx < 229376) tr2_one(W3, WT3h, WT3l, 256, 128, 256, idx - 196608);
        else if (idx < 262144) tr2_one(W4, WT4h, WT4l, 128, 200, 128, idx - 229376);
    }
}

// ---------------- deg: ONE packed per-dst counter (cnt3 lo16 | cntP hi16) ----------------
// Single atomic per edge to a 200KB array (was two 200KB arrays + divergent
// branch) -> halved atomic cacheline footprint. slot[e] = within-class slot
// | (ptype<<28); type-3 edges in [0,d3), proto edges [d3,deg).

__global__ void k_deg(const int* __restrict__ src, const int* __restrict__ dst, int E,
                      const unsigned char* __restrict__ gidb,
                      int* __restrict__ cnt, int* __restrict__ slot) {
    int e = blockIdx.x * 256 + threadIdx.x;
    if (e >= E) return;
    int d = dst[e];
    int t = gidb[src[e]];  // 50KB table, L2-hot
    uint inc = (t == 3) ? 1u : 0x10000u;
    uint old = (uint)atomicAdd(&cnt[d], (int)inc);
    int s = (t == 3) ? (int)(old & 0xffffu) : (int)(old >> 16);
    slot[e] = s | (t << 28);
}

// ---------------- scanA: block-local prefix + dinv + cnt3 extract + group counts ----------------

__global__ void k_scanA(const int* __restrict__ cnt,
                        int* __restrict__ cnt3x, int* __restrict__ degT,
                        int* __restrict__ offs,
                        int* __restrict__ bsum, float* __restrict__ dinv,
                        const int* __restrict__ gid, int* __restrict__ gcnt, int NN) {
    __shared__ int lds[256];
    __shared__ int cnt4[4];
    int t = threadIdx.x;
    if (t < 4) cnt4[t] = 0;
    int i = blockIdx.x * 256 + t;
    int v = 0;
    if (i < NN) {
        uint c = (uint)cnt[i];
        int d3 = (int)(c & 0xffffu);
        v = d3 + (int)(c >> 16);
        cnt3x[i] = d3;
        degT[i] = v;
        dinv[i] = 1.0f / sqrtf((float)(v + 1));  // +1 self loop
    }
    lds[t] = v;
    __syncthreads();
    if (i < NN) atomicAdd(&cnt4[gid[i]], 1);
    for (int d = 1; d < 256; d <<= 1) {
        int u = (t >= d) ? lds[t - d] : 0;
        __syncthreads();
        lds[t] += u;
        __syncthreads();
    }
    if (i < NN) offs[i] = lds[t] - v;  // block-local exclusive
    if (t == 255) bsum[blockIdx.x] = lds[255];
    __syncthreads();
    if (t < 4 && cnt4[t]) atomicAdd(&gcnt[t], cnt4[t]);
}

// ---------------- fill: atomic-free placement, class-segmented slots ----------------

__global__ void k_fill(const int* __restrict__ src, const int* __restrict__ dst,
                       const int* __restrict__ slot, const int* __restrict__ cnt3, int E,
                       const float* __restrict__ dinv, const int* __restrict__ offs,
                       const int* __restrict__ bsum,
                       uint2* __restrict__ epk, int NN, int NB,
                       int* __restrict__ goffs) {
    __shared__ int sex[256];
    int t = threadIdx.x;
    int v = (t < NB) ? bsum[t] : 0;
    sex[t] = v;
    __syncthreads();
    for (int d = 1; d < 256; d <<= 1) {
        int u = (t >= d) ? sex[t - d] : 0;
        __syncthreads();
        sex[t] += u;
        __syncthreads();
    }
    int incl = sex[t];
    __syncthreads();
    sex[t] = incl - v;  // exclusive prefix of bsum
    __syncthreads();
    int i = blockIdx.x * 256 + t;
    if (i < NN) goffs[i] = offs[i] + sex[i >> 8];
    if (i >= E) return;
    int s = src[i], d = dst[i];
    int sl = slot[i];
    int ty = sl >> 28;
    int sp = sl & 0x0FFFFFFF;
    int base = offs[d] + sex[d >> 8];
    int p = base + ((ty == 3) ? sp : (cnt3[d] + sp));
    epk[p] = make_uint2((uint)s | ((uint)ty << 30), __float_as_uint(dinv[s] * dinv[d]));
}

// ---------------- aggregation ----------------
// r2-r5 findings: all D=256 agg variants (fetch 160-188MB, 5 different issue
// structures) run at ~59.8us; D=128 at ~half => time ~ total request bytes
// (E x row bytes) delivered at ~7 TB/s (mixed L2-hit/HBM-miss random stream).
// Not HBM-BW, not L2-BW, not VALU. Aggs are at their structural floor at
// bf16 row width; leave alone.
// epk.x carries src | (ptype<<30); mask with 0x3FFFFFFF when gathering.

__device__ __forceinline__ uint2 ldnt_u2(const uint2* p) {
    union { unsigned long long ll; uint2 v; } r;
    r.ll = __builtin_nontemporal_load((const unsigned long long*)p);
    return r.v;
}

__device__ __forceinline__ void fma2(uint u, float w, float& a0, float& a1) {
    union { uint u; float f; } lo, hi;
    lo.u = u << 16;           // bf16 low element -> f32
    hi.u = u & 0xffff0000u;   // bf16 high element -> f32
    a0 = fmaf(w, lo.f, a0);
    a1 = fmaf(w, hi.f, a1);
}

template <int UN, int LD>
__device__ __forceinline__ void agg_step(const ushort* __restrict__ Hc,
                                         const uint2* __restrict__ epk, int e,
                                         float& a0, float& a1) {
    uint2 q[UN];
#pragma unroll
    for (int i = 0; i < UN; ++i) q[i] = ldnt_u2(epk + e + i);
    uint u[UN];
#pragma unroll
    for (int i = 0; i < UN; ++i)
        u[i] = *(const uint*)(Hc + (size_t)(q[i].x & 0x3FFFFFFFu) * LD);
#pragma unroll
    for (int i = 0; i < UN; ++i) fma2(u[i], __uint_as_float(q[i].y), a0, a1);
}

// One wave per node per 128-col slice; slice = blockIdx % NSL (NSL | 8) pins
// slices to XCD classes (r4: cuts fetch 187->160MB, time-neutral; kept).
template <int LD, int NSL, bool BR>
__global__ __launch_bounds__(256) void k_aggs(
        const ushort* __restrict__ H, ushort* __restrict__ outb,
        const float* __restrict__ dinv, const int* __restrict__ offs,
        const int* __restrict__ deg, const uint2* __restrict__ epk,
        const float* __restrict__ bias, int NN, int NNpad) {
    int slice = (NSL > 1) ? (int)(blockIdx.x % NSL) : 0;
    int nb = (NSL > 1) ? (int)(blockIdx.x / NSL) : (int)blockIdx.x;
    int wv = threadIdx.x >> 6;
    int wid = nb * 4 + wv;
    int lane = threadIdx.x & 63;
    if (wid >= NNpad) return;
    int c0 = slice * 128 + lane * 2;
    ushort* op = outb + (size_t)wid * LD + c0;
    if (wid >= NN) {  // zero pad rows (this slice's 256B)
        __builtin_nontemporal_store(0u, (uint*)op);
        return;
    }
    const ushort* Hc = H + c0;
    float a0 = 0.0f, a1 = 0.0f;
    {   // self-loop term
        float di = dinv[wid];
        float sw = di * di;
        uint u = *(const uint*)(Hc + (size_t)wid * LD);
        fma2(u, sw, a0, a1);
    }
    int e = offs[wid];
    int end = e + deg[wid];
    for (; e + 16 <= end; e += 16) agg_step<16, LD>(Hc, epk, e, a0, a1);
    if (e + 8 <= end) { agg_step<8, LD>(Hc, epk, e, a0, a1); e += 8; }
    if (e + 4 <= end) { agg_step<4, LD>(Hc, epk, e, a0, a1); e += 4; }
    if (e + 2 <= end) { agg_step<2, LD>(Hc, epk, e, a0, a1); e += 2; }
    if (e < end) agg_step<1, LD>(Hc, epk, e, a0, a1);
    if (BR) {
        a0 = fmaxf(a0 + bias[c0], 0.0f);
        a1 = fmaxf(a1 + bias[c0 + 1], 0.0f);
    }
    uint w = (uint)f2bf(a0) | ((uint)f2bf(a1) << 16);
    __builtin_nontemporal_store(w, (uint*)op);
}

// ---------------- agg1: first-layer aggregation exploiting prototype rows ----------------
// ~75% of srcs are one of 3 prototype rows -> their contribution is
// nf_t * (sum of norms). Edge list is class-segmented per dst: [0,d3) type-3
// (dense branch-free gathers), [d3,deg) proto (stream norms only).

template <int UNB>
__device__ __forceinline__ void proto_step(const uint2* __restrict__ epk, int e,
                                           float& s0, float& s1, float& s2) {
    uint2 q[UNB];
#pragma unroll
    for (int i = 0; i < UNB; ++i) q[i] = ldnt_u2(epk + e + i);
#pragma unroll
    for (int i = 0; i < UNB; ++i) {
        int t = (int)(q[i].x >> 30);
        float w = __uint_as_float(q[i].y);
        s0 += (t == 0) ? w : 0.f;
        s1 += (t == 1) ? w : 0.f;
        s2 += (t == 2) ? w : 0.f;
    }
}

__global__ __launch_bounds__(256) void k_agg1(
        const ushort* __restrict__ H, const float* __restrict__ nf,
        ushort* __restrict__ outb,
        const float* __restrict__ dinv, const int* __restrict__ offs,
        const int* __restrict__ degT, const int* __restrict__ cnt3,
        const uint2* __restrict__ epk, int NN, int NNpad) {
    int wid = (int)((blockIdx.x * blockDim.x + threadIdx.x) >> 6);
    int lane = threadIdx.x & 63;
    if (wid >= NNpad) return;
    int c0 = lane * 2;
    ushort* op = outb + (size_t)wid * 128 + c0;
    if (wid >= NN) {
        __builtin_nontemporal_store(0u, (uint*)op);
        return;
    }
    const ushort* Hc = H + c0;
    float a0 = 0.0f, a1 = 0.0f;
    {   // self-loop term (xb holds bf16 features for ALL node types)
        float di = dinv[wid];
        float sw = di * di;
        uint u = *(const uint*)(Hc + (size_t)wid * 128);
        fma2(u, sw, a0, a1);
    }
    int beg = offs[wid];
    int d3 = cnt3[wid];
    int dT = degT[wid];
    // segment A: type-3 srcs -> gather (dense, full MLP)
    int e = beg, endA = beg + d3;
    for (; e + 8 <= endA; e += 8) agg_step<8, 128>(Hc, epk, e, a0, a1);
    if (e + 4 <= endA) { agg_step<4, 128>(Hc, epk, e, a0, a1); e += 4; }
    if (e + 2 <= endA) { agg_step<2, 128>(Hc, epk, e, a0, a1); e += 2; }
    if (e < endA) agg_step<1, 128>(Hc, epk, e, a0, a1);
    // segment B: proto srcs -> per-type norm sums (no gathers)
    float s0 = 0.f, s1 = 0.f, s2 = 0.f;
    e = endA;
    int endB = beg + dT;
    for (; e + 8 <= endB; e += 8) proto_step<8>(epk, e, s0, s1, s2);
    if (e + 4 <= endB) { proto_step<4>(epk, e, s0, s1, s2); e += 4; }
    if (e + 2 <= endB) { proto_step<2>(epk, e, s0, s1, s2); e += 2; }
    if (e < endB) proto_step<1>(epk, e, s0, s1, s2);
    // fold prototype contributions (bf16-roundtripped to match xb rows)
    if (c0 < 100) {
        float p00 = bf2f(f2bf(nf[c0]));
        float p01 = bf2f(f2bf(nf[c0 + 1]));
        float p10 = bf2f(f2bf(nf[100 + c0]));
        float p11 = bf2f(f2bf(nf[100 + c0 + 1]));
        float p20 = bf2f(f2bf(nf[200 + c0]));
        float p21 = bf2f(f2bf(nf[200 + c0 + 1]));
        a0 += s0 * p00 + s1 * p10 + s2 * p20;
        a1 += s0 * p01 + s1 * p11 + s2 * p21;
    }
    uint w = (uint)f2bf(a0) | ((uint)f2bf(a1) << 16);
    __builtin_nontemporal_store(w, (uint*)op);
}

// ---------------- MFMA GEMM: double-buffered staging with counted vmcnt (T3/T4) ----------------
// r8: this structure beat the barrier-drain loop by 13.5us total. Frozen.

template <bool BR, int OUT>
__global__ __launch_bounds__(256) void k_gemm(
        const ushort* __restrict__ A,
        const ushort* __restrict__ Bh, const ushort* __restrict__ Bl,
        const float* __restrict__ bias,
        ushort* __restrict__ Cb,
        int Nc, int K, int tNb,
        const int* __restrict__ gid, float* __restrict__ gsum, int NN) {
    __shared__ union {
        ushort st[2][3][128 * 32];  // [dbuf][plane A/Bh/Bl][row*32 + col]
        float epi[64 * 132];
    } sm;
    __shared__ int gcode[64];
    int bm = blockIdx.x / tNb, bn = blockIdx.x % tNb;
    int m0 = bm * 128, n0 = bn * 128;
    int wv = threadIdx.x >> 6, lane = threadIdx.x & 63;
    int l15 = lane & 15, quad = lane >> 4;
    const ushort* gsrc;
    int plane, woff, ng;
    if (wv == 0)      { gsrc = A  + (size_t)m0 * K;        plane = 0; woff = 0;    ng = 4; }
    else if (wv == 1) { gsrc = A  + (size_t)(m0 + 64) * K; plane = 0; woff = 2048; ng = 4; }
    else if (wv == 2) { gsrc = Bh + (size_t)n0 * K;        plane = 1; woff = 0;    ng = 8; }
    else              { gsrc = Bl + (size_t)n0 * K;        plane = 2; woff = 0;    ng = 8; }
    const ushort* gBase = gsrc + (size_t)(lane >> 2) * K + (lane & 3) * 8;
    ushort* lBase = &sm.st[0][0][0] + plane * 4096 + woff;
    const ushort* sAll = &sm.st[0][0][0];
    int wm = (wv >> 1) * 64, wn = (wv & 1) * 64;
    f32x4 acc[4][4] = {};
    int nk = K >> 5;
    // prologue: stage K-step 0 into buffer 0
    for (int i = 0; i < ng; ++i)
        gll(gBase + (size_t)(16 * i) * K, lBase + i * 512);
    for (int k = 0; k < nk; ++k) {
        int cur = k & 1;
        if (k + 1 < nk) {
            // issue next tile into the other buffer; do NOT wait for it
            ushort* l2 = lBase + (cur ^ 1) * 12288;
            const ushort* g2 = gBase + (k + 1) * 32;
            for (int i = 0; i < ng; ++i)
                gll(g2 + (size_t)(16 * i) * K, l2 + i * 512);
            if (ng == 4) asm volatile("s_waitcnt vmcnt(4)" ::: "memory");
            else         asm volatile("s_waitcnt vmcnt(8)" ::: "memory");
        } else {
            asm volatile("s_waitcnt vmcnt(0)" ::: "memory");
        }
        __builtin_amdgcn_s_barrier();          // all waves' cur-buffer loads landed
        __builtin_amdgcn_sched_barrier(0);     // rule 18: pin reads below the wait
        const ushort* sA_  = sAll + cur * 12288;
        const ushort* sBh_ = sA_ + 4096;
        const ushort* sBl_ = sA_ + 8192;
        bf16x8 Af[4], Bfh[4], Bfl[4];
#pragma unroll
        for (int i = 0; i < 4; ++i) {
            int ra = (wm + 16 * i + l15) * 32 + quad * 8;
            int rb = (wn + 16 * i + l15) * 32 + quad * 8;
            Af[i]  = *(const bf16x8*)(sA_ + ra);
            Bfh[i] = *(const bf16x8*)(sBh_ + rb);
            Bfl[i] = *(const bf16x8*)(sBl_ + rb);
        }
#pragma unroll
        for (int mi = 0; mi < 4; ++mi)
#pragma unroll
            for (int ni = 0; ni < 4; ++ni) {
                acc[mi][ni] = __builtin_amdgcn_mfma_f32_16x16x32_bf16(Af[mi], Bfh[ni], acc[mi][ni], 0, 0, 0);
                acc[mi][ni] = __builtin_amdgcn_mfma_f32_16x16x32_bf16(Af[mi], Bfl[ni], acc[mi][ni], 0, 0, 0);
            }
        __builtin_amdgcn_s_barrier();          // all waves done reading cur buffer
    }
    __builtin_amdgcn_sched_barrier(0);
    float bia[4] = {0.f, 0.f, 0.f, 0.f};
    if (BR) {
#pragma unroll
        for (int ni = 0; ni < 4; ++ni) {
            int col = n0 + wn + 16 * ni + l15;
            if (col < Nc) bia[ni] = bias[col];
        }
    }
    float* epi = sm.epi;
    int t = threadIdx.x;
    float s0 = 0.f, s1 = 0.f, s2 = 0.f, s3 = 0.f;  // OUT==2 per-group sums
    int colR = t & 127, rg = t >> 7;
    for (int half = 0; half < 2; ++half) {
        if ((wv >> 1) == half) {
#pragma unroll
            for (int mi = 0; mi < 4; ++mi)
#pragma unroll
                for (int r = 0; r < 4; ++r) {
                    int rl = mi * 16 + quad * 4 + r;
#pragma unroll
                    for (int ni = 0; ni < 4; ++ni) {
                        float v = acc[mi][ni][r];
                        if (BR) v = fmaxf(v + bia[ni], 0.0f);
                        epi[rl * 132 + wn + ni * 16 + l15] = v;
                    }
                }
        }
        if (OUT == 2 && t < 64) {
            int grow = m0 + half * 64 + t;
            gcode[t] = (grow < NN) ? gid[grow] : -1;
        }
        __syncthreads();
        if (OUT == 2) {
#pragma unroll 4
            for (int r = 0; r < 32; ++r) {
                int row = rg * 32 + r;
                int g = gcode[row];
                float v = epi[row * 132 + colR];
                s0 += (g == 0) ? v : 0.f;
                s1 += (g == 1) ? v : 0.f;
                s2 += (g == 2) ? v : 0.f;
                s3 += (g == 3) ? v : 0.f;
            }
        } else {
#pragma unroll
            for (int j = 0; j < 16; ++j) {
                int e = (j * 256 + t) * 2;
                int rl = e >> 7, cl = e & 127;
                int grow = m0 + half * 64 + rl;
                int gcol = n0 + cl;
                float v0 = epi[rl * 132 + cl];
                float v1 = epi[rl * 132 + cl + 1];
                *(uint*)&Cb[(size_t)grow * Nc + gcol] = (uint)f2bf(v0) | ((uint)f2bf(v1) << 16);
            }
        }
        __syncthreads();
    }
    if (OUT == 2) {
        if (rg == 1) {
            epi[colR * 4 + 0] = s0; epi[colR * 4 + 1] = s1;
            epi[colR * 4 + 2] = s2; epi[colR * 4 + 3] = s3;
        }
        __syncthreads();
        if (rg == 0) {
            s0 += epi[colR * 4 + 0]; s1 += epi[colR * 4 + 1];
            s2 += epi[colR * 4 + 2]; s3 += epi[colR * 4 + 3];
            int gcol = n0 + colR;
            if (gcol < Nc) {
                atomicAdd(&gsum[0 * Nc + gcol], s0);
                atomicAdd(&gsum[1 * Nc + gcol], s1);
                atomicAdd(&gsum[2 * Nc + gcol], s2);
                atomicAdd(&gsum[3 * Nc + gcol], s3);
            }
        }
    }
}

// ---------------- final: divide by precomputed group counts ----------------

__global__ void k_final(const float* __restrict__ gsum, const int* __restrict__ gcnt,
                        float* __restrict__ out) {
    int j = blockIdx.x * blockDim.x + threadIdx.x;
    if (j >= 800) return;
    int c = gcnt[j / 200];
    out[j] = (c > 0) ? gsum[j] / (float)c : 0.0f;
}

// ---------------- launch ----------------

extern "C" void kernel_launch(void* const* d_in, const int* in_sizes, int n_in,
                              void* d_out, int out_size, void* d_ws, size_t ws_size,
                              hipStream_t stream) {
    const float* x  = (const float*)d_in[0];
    const float* nf = (const float*)d_in[1];
    const int* ei   = (const int*)d_in[2];
    const float* W1 = (const float*)d_in[3];
    const float* b1 = (const float*)d_in[4];
    const float* W2 = (const float*)d_in[5];
    const float* b2 = (const float*)d_in[6];
    const float* W3 = (const float*)d_in[7];
    const float* b3 = (const float*)d_in[8];
    const float* W4 = (const float*)d_in[9];
    const float* b4 = (const float*)d_in[10];
    float* out = (float*)d_out;

    const int NN = in_sizes[0] / 100;  // 50000
    const int E  = in_sizes[2] / 2;    // 800000
    const int MPAD = ((NN + 127) / 128) * 128;  // 50048
    const int NB = (NN + 255) / 256;   // scan blocks (196 <= 256)
    const int PB = (NN + 3) / 4;       // prep blocks
    const int EB = (E + 255) / 256;    // deg/fill blocks
    const int TB = 1024;               // weight-split blocks
    const int* src = ei;
    const int* dst = ei + E;

    char* p = (char*)d_ws;
    auto alloc = [&](size_t bytes) -> char* {
        char* r = p;
        p += (bytes + 255) & ~(size_t)255;
        return r;
    };
    char* zz = p;
    int*   cnt  = (int*)alloc((size_t)NN * 4);   // packed: cnt3 lo16 | cntP hi16
    float* gsum = (float*)alloc(800 * 4);
    int*   gcnt = (int*)alloc(256);
    size_t zz_bytes = (size_t)(p - zz);
    int*   cnt3x = (int*)alloc((size_t)NN * 4);  // extracted cnt3 (scanA)
    int*   degT = (int*)alloc((size_t)NN * 4);
    int*   slot = (int*)alloc((size_t)E * 4);
    float* dinv = (float*)alloc((size_t)NN * 4);
    int*   offs = (int*)alloc((size_t)NN * 4);   // block-local prefix (scanA)
    int*   goffs = (int*)alloc((size_t)NN * 4);  // global prefix (fill)
    int*   bsum = (int*)alloc(1024);
    int*   gid  = (int*)alloc((size_t)NN * 4);
    unsigned char* gidb = (unsigned char*)alloc((size_t)NN);
    uint2* epk  = (uint2*)alloc((size_t)E * 8);
    ushort* WT1h = (ushort*)alloc((size_t)512 * 128 * 2);
    ushort* WT1l = (ushort*)alloc((size_t)512 * 128 * 2);
    ushort* WT2h = (ushort*)alloc((size_t)256 * 512 * 2);
    ushort* WT2l = (ushort*)alloc((size_t)256 * 512 * 2);
    ushort* WT3h = (ushort*)alloc((size_t)128 * 256 * 2);
    ushort* WT3l = (ushort*)alloc((size_t)128 * 256 * 2);
    ushort* WT4h = (ushort*)alloc((size_t)256 * 128 * 2);
    ushort* WT4l = (ushort*)alloc((size_t)256 * 128 * 2);
    ushort* xb = (ushort*)alloc((size_t)NN * 128 * 2);
    ushort* P1 = (ushort*)alloc((size_t)MPAD * 128 * 2);
    ushort* H1 = (ushort*)alloc((size_t)MPAD * 512 * 2);
    ushort* T2 = (ushort*)alloc((size_t)MPAD * 256 * 2);
    ushort* H2 = (ushort*)alloc((size_t)MPAD * 256 * 2);
    ushort* T3 = (ushort*)alloc((size_t)MPAD * 128 * 2);
    ushort* H3 = (ushort*)alloc((size_t)MPAD * 128 * 2);
    ushort* P4 = (ushort*)alloc((size_t)MPAD * 128 * 2);

    hipMemsetAsync(zz, 0, zz_bytes, stream);

    k_prepw<<<PB + TB, 256, 0, stream>>>((const uint*)x, (const uint*)nf, xb, gid, gidb, NN, PB,
        W1, W2, W3, W4, WT1h, WT1l, WT2h, WT2l, WT3h, WT3l, WT4h, WT4l);
    k_deg<<<EB, 256, 0, stream>>>(src, dst, E, gidb, cnt, slot);
    k_scanA<<<NB, 256, 0, stream>>>(cnt, cnt3x, degT, offs, bsum, dinv, gid, gcnt, NN);
    k_fill<<<EB, 256, 0, stream>>>(src, dst, slot, cnt3x, E, dinv, offs, bsum, epk, NN, NB, goffs);

    int aggBlocks = MPAD / 4;  // one wave per node (per slice)
    int mB = MPAD / 128;

    // P1 = agg(xb) -> bf16 [MPAD,128]; prototype shortcut (gather only type-3 srcs)
    k_agg1<<<aggBlocks, 256, 0, stream>>>(xb, nf, P1, dinv, goffs, degT, cnt3x, epk, NN, MPAD);
    // H1 = relu(P1 @ W1 + b1) -> bf16 [MPAD,512]
    k_gemm<true, 1><<<mB * 4, 256, 0, stream>>>(P1, WT1h, WT1l, b1, H1, 512, 128, 4, nullptr, nullptr, 0);
    // T2 = H1 @ W2 -> bf16 [MPAD,256]
    k_gemm<false, 1><<<mB * 2, 256, 0, stream>>>(H1, WT2h, WT2l, nullptr, T2, 256, 512, 2, nullptr, nullptr, 0);
    // H2 = relu(agg(T2) + b2) -> bf16 [MPAD,256], 2 XCD-pinned 128-col slices
    k_aggs<256, 2, true><<<aggBlocks * 2, 256, 0, stream>>>(T2, H2, dinv, goffs, degT, epk, b2, NN, MPAD);
    // T3 = H2 @ W3 -> bf16 [MPAD,128]
    k_gemm<false, 1><<<mB * 1, 256, 0, stream>>>(H2, WT3h, WT3l, nullptr, T3, 128, 256, 1, nullptr, nullptr, 0);
    // H3 = relu(agg(T3) + b3) -> bf16 [MPAD,128]
    k_aggs<128, 1, true><<<aggBlocks, 256, 0, stream>>>(T3, H3, dinv, goffs, degT, epk, b3, NN, MPAD);
    // P4 = agg(H3) -> bf16 [MPAD,128]
    k_aggs<128, 1, false><<<aggBlocks, 256, 0, stream>>>(H3, P4, dinv, goffs, degT, epk, nullptr, NN, MPAD);
    // relu(P4 @ W4 + b4) -> per-group reduction into gsum (no H4 tensor)
    k_gemm<true, 2><<<mB * 2, 256, 0, stream>>>(P4, WT4h, WT4l, b4, nullptr, 200, 128, 2, gid, gsum, NN);

    k_final<<<4, 256, 0, stream>>>(gsum, gcnt, out);
}

// Round 10
// 403.506 us; speedup vs baseline: 1.0807x; 1.0459x over previous
//
#include <hip/hip_runtime.h>
#include <stdint.h>

typedef __attribute__((ext_vector_type(8))) short bf16x8;
typedef __attribute__((ext_vector_type(4))) float f32x4;

__device__ __forceinline__ float bf2f(ushort h) {
    union { uint u; float f; } v; v.u = ((uint)h) << 16; return v.f;
}
__device__ __forceinline__ ushort f2bf(float f) {
    union { float f; uint u; } v; v.f = f;
    uint u = v.u;
    return (ushort)((u + 0x7fffu + ((u >> 16) & 1u)) >> 16);
}

// async global->LDS, 16B per lane; LDS dest = wave-uniform base + lane*16
__device__ __forceinline__ void gll(const ushort* g, ushort* l) {
    __builtin_amdgcn_global_load_lds(
        (const __attribute__((address_space(1))) void*)g,
        (__attribute__((address_space(3))) void*)l, 16, 0, 0);
}

// ---------------- prep+wsplit merged: one dispatch, independent sections ----------------
// r10: W -> single bf16 plane (hi only). A-operands are already bf16 single
// plane, so product error is floored by A's quantization; Wlo doubled MFMA
// work + B staging for sub-dominant precision. absmax expected ~2-4e-3.

__device__ __forceinline__ void tr1_one(const float* __restrict__ W,
                                        ushort* __restrict__ WTh,
                                        int K, int Nc, int KP, int idx) {
    int n = idx / KP, k = idx % KP;
    float w = (n < Nc && k < K) ? W[(size_t)k * Nc + n] : 0.0f;
    WTh[idx] = f2bf(w);
}

__global__ void k_prepw(const uint* __restrict__ xu, const uint* __restrict__ nfu,
                        ushort* __restrict__ xb, int* __restrict__ gid,
                        unsigned char* __restrict__ gidb, int NN, int PB,
                        const float* __restrict__ W1, const float* __restrict__ W2,
                        const float* __restrict__ W3, const float* __restrict__ W4,
                        ushort* __restrict__ WT1h, ushort* __restrict__ WT2h,
                        ushort* __restrict__ WT3h, ushort* __restrict__ WT4h) {
    int b = blockIdx.x;
    if (b < PB) {
        int wid = b * 4 + (threadIdx.x >> 6);
        int lane = threadIdx.x & 63;
        if (wid >= NN) return;
        int c0 = lane * 2;
        uint w = 0u;
        int m0 = 1, m1 = 1, m2 = 1;
        if (c0 < 100) {
            uint2 xv = *(const uint2*)&xu[(size_t)wid * 100 + c0];
            uint2 a = *(const uint2*)&nfu[c0];
            uint2 bb = *(const uint2*)&nfu[100 + c0];
            uint2 c = *(const uint2*)&nfu[200 + c0];
            m0 = (xv.x == a.x) & (xv.y == a.y);
            m1 = (xv.x == bb.x) & (xv.y == bb.y);
            m2 = (xv.x == c.x) & (xv.y == c.y);
            w = (uint)f2bf(__uint_as_float(xv.x)) | ((uint)f2bf(__uint_as_float(xv.y)) << 16);
        }
        int e0 = __all(m0), e1 = __all(m1), e2 = __all(m2);
        *(uint*)&xb[(size_t)wid * 128 + c0] = w;
        if (lane == 0) {
            // group id for the output reduction: 0/3/1/2 mapping (unchanged)
            gid[wid] = e0 ? 0 : (e1 ? 3 : (e2 ? 1 : 2));
            // prototype id for agg1: 0,1,2 = nf row index, 3 = random features
            gidb[wid] = (unsigned char)(e0 ? 0 : (e1 ? 1 : (e2 ? 2 : 3)));
        }
    } else {
        int idx = (b - PB) * 256 + threadIdx.x;
        if (idx < 65536) tr1_one(W1, WT1h, 100, 512, 128, idx);
        else if (idx < 196608) tr1_one(W2, WT2h, 512, 256, 512, idx - 65536);
        else if (idx < 229376) tr1_one(W3, WT3h, 256, 128, 256, idx - 196608);
        else if (idx < 262144) tr1_one(W4, WT4h, 128, 200, 128, idx - 229376);
    }
}

// ---------------- deg: ONE packed per-dst counter (cnt3 lo16 | cntP hi16) ----------------

__global__ void k_deg(const int* __restrict__ src, const int* __restrict__ dst, int E,
                      const unsigned char* __restrict__ gidb,
                      int* __restrict__ cnt, int* __restrict__ slot) {
    int e = blockIdx.x * 256 + threadIdx.x;
    if (e >= E) return;
    int d = dst[e];
    int t = gidb[src[e]];  // 50KB table, L2-hot
    uint inc = (t == 3) ? 1u : 0x10000u;
    uint old = (uint)atomicAdd(&cnt[d], (int)inc);
    int s = (t == 3) ? (int)(old & 0xffffu) : (int)(old >> 16);
    slot[e] = s | (t << 28);
}

// ---------------- scanA: block-local prefix + dinv + cnt3 extract + group counts ----------------

__global__ void k_scanA(const int* __restrict__ cnt,
                        int* __restrict__ cnt3x, int* __restrict__ degT,
                        int* __restrict__ offs,
                        int* __restrict__ bsum, float* __restrict__ dinv,
                        const int* __restrict__ gid, int* __restrict__ gcnt, int NN) {
    __shared__ int lds[256];
    __shared__ int cnt4[4];
    int t = threadIdx.x;
    if (t < 4) cnt4[t] = 0;
    int i = blockIdx.x * 256 + t;
    int v = 0;
    if (i < NN) {
        uint c = (uint)cnt[i];
        int d3 = (int)(c & 0xffffu);
        v = d3 + (int)(c >> 16);
        cnt3x[i] = d3;
        degT[i] = v;
        dinv[i] = 1.0f / sqrtf((float)(v + 1));  // +1 self loop
    }
    lds[t] = v;
    __syncthreads();
    if (i < NN) atomicAdd(&cnt4[gid[i]], 1);
    for (int d = 1; d < 256; d <<= 1) {
        int u = (t >= d) ? lds[t - d] : 0;
        __syncthreads();
        lds[t] += u;
        __syncthreads();
    }
    if (i < NN) offs[i] = lds[t] - v;  // block-local exclusive
    if (t == 255) bsum[blockIdx.x] = lds[255];
    __syncthreads();
    if (t < 4 && cnt4[t]) atomicAdd(&gcnt[t], cnt4[t]);
}

// ---------------- fill: atomic-free placement, class-segmented slots ----------------

__global__ void k_fill(const int* __restrict__ src, const int* __restrict__ dst,
                       const int* __restrict__ slot, const int* __restrict__ cnt3, int E,
                       const float* __restrict__ dinv, const int* __restrict__ offs,
                       const int* __restrict__ bsum,
                       uint2* __restrict__ epk, int NN, int NB,
                       int* __restrict__ goffs) {
    __shared__ int sex[256];
    int t = threadIdx.x;
    int v = (t < NB) ? bsum[t] : 0;
    sex[t] = v;
    __syncthreads();
    for (int d = 1; d < 256; d <<= 1) {
        int u = (t >= d) ? sex[t - d] : 0;
        __syncthreads();
        sex[t] += u;
        __syncthreads();
    }
    int incl = sex[t];
    __syncthreads();
    sex[t] = incl - v;  // exclusive prefix of bsum
    __syncthreads();
    int i = blockIdx.x * 256 + t;
    if (i < NN) goffs[i] = offs[i] + sex[i >> 8];
    if (i >= E) return;
    int s = src[i], d = dst[i];
    int sl = slot[i];
    int ty = sl >> 28;
    int sp = sl & 0x0FFFFFFF;
    int base = offs[d] + sex[d >> 8];
    int p = base + ((ty == 3) ? sp : (cnt3[d] + sp));
    epk[p] = make_uint2((uint)s | ((uint)ty << 30), __float_as_uint(dinv[s] * dinv[d]));
}

// ---------------- aggregation ----------------
// r2-r5: all agg variants pinned at time ~ total request bytes (E x row bytes)
// at ~7 TB/s delivered; r9: build phase at the same wall. Aggs frozen.
// epk.x carries src | (ptype<<30); mask with 0x3FFFFFFF when gathering.

__device__ __forceinline__ uint2 ldnt_u2(const uint2* p) {
    union { unsigned long long ll; uint2 v; } r;
    r.ll = __builtin_nontemporal_load((const unsigned long long*)p);
    return r.v;
}

__device__ __forceinline__ void fma2(uint u, float w, float& a0, float& a1) {
    union { uint u; float f; } lo, hi;
    lo.u = u << 16;           // bf16 low element -> f32
    hi.u = u & 0xffff0000u;   // bf16 high element -> f32
    a0 = fmaf(w, lo.f, a0);
    a1 = fmaf(w, hi.f, a1);
}

template <int UN, int LD>
__device__ __forceinline__ void agg_step(const ushort* __restrict__ Hc,
                                         const uint2* __restrict__ epk, int e,
                                         float& a0, float& a1) {
    uint2 q[UN];
#pragma unroll
    for (int i = 0; i < UN; ++i) q[i] = ldnt_u2(epk + e + i);
    uint u[UN];
#pragma unroll
    for (int i = 0; i < UN; ++i)
        u[i] = *(const uint*)(Hc + (size_t)(q[i].x & 0x3FFFFFFFu) * LD);
#pragma unroll
    for (int i = 0; i < UN; ++i) fma2(u[i], __uint_as_float(q[i].y), a0, a1);
}

// One wave per node per 128-col slice; slice = blockIdx % NSL (NSL | 8) pins
// slices to XCD classes (r4: cuts fetch 187->160MB, time-neutral; kept).
template <int LD, int NSL, bool BR>
__global__ __launch_bounds__(256) void k_aggs(
        const ushort* __restrict__ H, ushort* __restrict__ outb,
        const float* __restrict__ dinv, const int* __restrict__ offs,
        const int* __restrict__ deg, const uint2* __restrict__ epk,
        const float* __restrict__ bias, int NN, int NNpad) {
    int slice = (NSL > 1) ? (int)(blockIdx.x % NSL) : 0;
    int nb = (NSL > 1) ? (int)(blockIdx.x / NSL) : (int)blockIdx.x;
    int wv = threadIdx.x >> 6;
    int wid = nb * 4 + wv;
    int lane = threadIdx.x & 63;
    if (wid >= NNpad) return;
    int c0 = slice * 128 + lane * 2;
    ushort* op = outb + (size_t)wid * LD + c0;
    if (wid >= NN) {  // zero pad rows (this slice's 256B)
        __builtin_nontemporal_store(0u, (uint*)op);
        return;
    }
    const ushort* Hc = H + c0;
    float a0 = 0.0f, a1 = 0.0f;
    {   // self-loop term
        float di = dinv[wid];
        float sw = di * di;
        uint u = *(const uint*)(Hc + (size_t)wid * LD);
        fma2(u, sw, a0, a1);
    }
    int e = offs[wid];
    int end = e + deg[wid];
    for (; e + 16 <= end; e += 16) agg_step<16, LD>(Hc, epk, e, a0, a1);
    if (e + 8 <= end) { agg_step<8, LD>(Hc, epk, e, a0, a1); e += 8; }
    if (e + 4 <= end) { agg_step<4, LD>(Hc, epk, e, a0, a1); e += 4; }
    if (e + 2 <= end) { agg_step<2, LD>(Hc, epk, e, a0, a1); e += 2; }
    if (e < end) agg_step<1, LD>(Hc, epk, e, a0, a1);
    if (BR) {
        a0 = fmaxf(a0 + bias[c0], 0.0f);
        a1 = fmaxf(a1 + bias[c0 + 1], 0.0f);
    }
    uint w = (uint)f2bf(a0) | ((uint)f2bf(a1) << 16);
    __builtin_nontemporal_store(w, (uint*)op);
}

// ---------------- agg1: first-layer aggregation exploiting prototype rows ----------------

template <int UNB>
__device__ __forceinline__ void proto_step(const uint2* __restrict__ epk, int e,
                                           float& s0, float& s1, float& s2) {
    uint2 q[UNB];
#pragma unroll
    for (int i = 0; i < UNB; ++i) q[i] = ldnt_u2(epk + e + i);
#pragma unroll
    for (int i = 0; i < UNB; ++i) {
        int t = (int)(q[i].x >> 30);
        float w = __uint_as_float(q[i].y);
        s0 += (t == 0) ? w : 0.f;
        s1 += (t == 1) ? w : 0.f;
        s2 += (t == 2) ? w : 0.f;
    }
}

__global__ __launch_bounds__(256) void k_agg1(
        const ushort* __restrict__ H, const float* __restrict__ nf,
        ushort* __restrict__ outb,
        const float* __restrict__ dinv, const int* __restrict__ offs,
        const int* __restrict__ degT, const int* __restrict__ cnt3,
        const uint2* __restrict__ epk, int NN, int NNpad) {
    int wid = (int)((blockIdx.x * blockDim.x + threadIdx.x) >> 6);
    int lane = threadIdx.x & 63;
    if (wid >= NNpad) return;
    int c0 = lane * 2;
    ushort* op = outb + (size_t)wid * 128 + c0;
    if (wid >= NN) {
        __builtin_nontemporal_store(0u, (uint*)op);
        return;
    }
    const ushort* Hc = H + c0;
    float a0 = 0.0f, a1 = 0.0f;
    {   // self-loop term (xb holds bf16 features for ALL node types)
        float di = dinv[wid];
        float sw = di * di;
        uint u = *(const uint*)(Hc + (size_t)wid * 128);
        fma2(u, sw, a0, a1);
    }
    int beg = offs[wid];
    int d3 = cnt3[wid];
    int dT = degT[wid];
    // segment A: type-3 srcs -> gather (dense, full MLP)
    int e = beg, endA = beg + d3;
    for (; e + 8 <= endA; e += 8) agg_step<8, 128>(Hc, epk, e, a0, a1);
    if (e + 4 <= endA) { agg_step<4, 128>(Hc, epk, e, a0, a1); e += 4; }
    if (e + 2 <= endA) { agg_step<2, 128>(Hc, epk, e, a0, a1); e += 2; }
    if (e < endA) agg_step<1, 128>(Hc, epk, e, a0, a1);
    // segment B: proto srcs -> per-type norm sums (no gathers)
    float s0 = 0.f, s1 = 0.f, s2 = 0.f;
    e = endA;
    int endB = beg + dT;
    for (; e + 8 <= endB; e += 8) proto_step<8>(epk, e, s0, s1, s2);
    if (e + 4 <= endB) { proto_step<4>(epk, e, s0, s1, s2); e += 4; }
    if (e + 2 <= endB) { proto_step<2>(epk, e, s0, s1, s2); e += 2; }
    if (e < endB) proto_step<1>(epk, e, s0, s1, s2);
    // fold prototype contributions (bf16-roundtripped to match xb rows)
    if (c0 < 100) {
        float p00 = bf2f(f2bf(nf[c0]));
        float p01 = bf2f(f2bf(nf[c0 + 1]));
        float p10 = bf2f(f2bf(nf[100 + c0]));
        float p11 = bf2f(f2bf(nf[100 + c0 + 1]));
        float p20 = bf2f(f2bf(nf[200 + c0]));
        float p21 = bf2f(f2bf(nf[200 + c0 + 1]));
        a0 += s0 * p00 + s1 * p10 + s2 * p20;
        a1 += s0 * p01 + s1 * p11 + s2 * p21;
    }
    uint w = (uint)f2bf(a0) | ((uint)f2bf(a1) << 16);
    __builtin_nontemporal_store(w, (uint*)op);
}

// ---------------- MFMA GEMM: single-plane W, double-buffered counted-vmcnt ----------------
// r8: counted-vmcnt dbuf beat barrier-drain (+13.5us). r10: drop Wlo plane —
// 16 MFMA per K-step (was 32), B staging halved, all 4 waves stage 4 lines
// (uniform vmcnt(4)), LDS 48->34KB (3->4 blocks/CU).

template <bool BR, int OUT>
__global__ __launch_bounds__(256) void k_gemm(
        const ushort* __restrict__ A, const ushort* __restrict__ Bh,
        const float* __restrict__ bias, ushort* __restrict__ Cb,
        int Nc, int K, int tNb,
        const int* __restrict__ gid, float* __restrict__ gsum, int NN) {
    __shared__ union {
        ushort st[2][2][128 * 32];  // [dbuf][plane A/B][row*32 + col] = 32KB
        float epi[64 * 132];
    } sm;
    __shared__ int gcode[64];
    int bm = blockIdx.x / tNb, bn = blockIdx.x % tNb;
    int m0 = bm * 128, n0 = bn * 128;
    int wv = threadIdx.x >> 6, lane = threadIdx.x & 63;
    int l15 = lane & 15, quad = lane >> 4;
    const ushort* gsrc;
    int plane, woff;
    if (wv == 0)      { gsrc = A  + (size_t)m0 * K;         plane = 0; woff = 0;    }
    else if (wv == 1) { gsrc = A  + (size_t)(m0 + 64) * K;  plane = 0; woff = 2048; }
    else if (wv == 2) { gsrc = Bh + (size_t)n0 * K;         plane = 1; woff = 0;    }
    else              { gsrc = Bh + (size_t)(n0 + 64) * K;  plane = 1; woff = 2048; }
    const ushort* gBase = gsrc + (size_t)(lane >> 2) * K + (lane & 3) * 8;
    ushort* lBase = &sm.st[0][0][0] + plane * 4096 + woff;
    const ushort* sAll = &sm.st[0][0][0];
    int wm = (wv >> 1) * 64, wn = (wv & 1) * 64;
    f32x4 acc[4][4] = {};
    int nk = K >> 5;
    // prologue: stage K-step 0 into buffer 0 (4 lines per wave)
    for (int i = 0; i < 4; ++i)
        gll(gBase + (size_t)(16 * i) * K, lBase + i * 512);
    for (int k = 0; k < nk; ++k) {
        int cur = k & 1;
        if (k + 1 < nk) {
            // issue next tile into the other buffer; do NOT wait for it
            ushort* l2 = lBase + (cur ^ 1) * 8192;
            const ushort* g2 = gBase + (k + 1) * 32;
            for (int i = 0; i < 4; ++i)
                gll(g2 + (size_t)(16 * i) * K, l2 + i * 512);
            asm volatile("s_waitcnt vmcnt(4)" ::: "memory");
        } else {
            asm volatile("s_waitcnt vmcnt(0)" ::: "memory");
        }
        __builtin_amdgcn_s_barrier();          // all waves' cur-buffer loads landed
        __builtin_amdgcn_sched_barrier(0);     // rule 18: pin reads below the wait
        const ushort* sA_ = sAll + cur * 8192;
        const ushort* sB_ = sA_ + 4096;
        bf16x8 Af[4], Bf[4];
#pragma unroll
        for (int i = 0; i < 4; ++i) {
            int ra = (wm + 16 * i + l15) * 32 + quad * 8;
            int rb = (wn + 16 * i + l15) * 32 + quad * 8;
            Af[i] = *(const bf16x8*)(sA_ + ra);
            Bf[i] = *(const bf16x8*)(sB_ + rb);
        }
#pragma unroll
        for (int mi = 0; mi < 4; ++mi)
#pragma unroll
            for (int ni = 0; ni < 4; ++ni)
                acc[mi][ni] = __builtin_amdgcn_mfma_f32_16x16x32_bf16(Af[mi], Bf[ni], acc[mi][ni], 0, 0, 0);
        __builtin_amdgcn_s_barrier();          // all waves done reading cur buffer
    }
    __builtin_amdgcn_sched_barrier(0);
    float bia[4] = {0.f, 0.f, 0.f, 0.f};
    if (BR) {
#pragma unroll
        for (int ni = 0; ni < 4; ++ni) {
            int col = n0 + wn + 16 * ni + l15;
            if (col < Nc) bia[ni] = bias[col];
        }
    }
    float* epi = sm.epi;
    int t = threadIdx.x;
    float s0 = 0.f, s1 = 0.f, s2 = 0.f, s3 = 0.f;  // OUT==2 per-group sums
    int colR = t & 127, rg = t >> 7;
    for (int half = 0; half < 2; ++half) {
        if ((wv >> 1) == half) {
#pragma unroll
            for (int mi = 0; mi < 4; ++mi)
#pragma unroll
                for (int r = 0; r < 4; ++r) {
                    int rl = mi * 16 + quad * 4 + r;
#pragma unroll
                    for (int ni = 0; ni < 4; ++ni) {
                        float v = acc[mi][ni][r];
                        if (BR) v = fmaxf(v + bia[ni], 0.0f);
                        epi[rl * 132 + wn + ni * 16 + l15] = v;
                    }
                }
        }
        if (OUT == 2 && t < 64) {
            int grow = m0 + half * 64 + t;
            gcode[t] = (grow < NN) ? gid[grow] : -1;
        }
        __syncthreads();
        if (OUT == 2) {
#pragma unroll 4
            for (int r = 0; r < 32; ++r) {
                int row = rg * 32 + r;
                int g = gcode[row];
                float v = epi[row * 132 + colR];
                s0 += (g == 0) ? v : 0.f;
                s1 += (g == 1) ? v : 0.f;
                s2 += (g == 2) ? v : 0.f;
                s3 += (g == 3) ? v : 0.f;
            }
        } else {
#pragma unroll
            for (int j = 0; j < 16; ++j) {
                int e = (j * 256 + t) * 2;
                int rl = e >> 7, cl = e & 127;
                int grow = m0 + half * 64 + rl;
                int gcol = n0 + cl;
                float v0 = epi[rl * 132 + cl];
                float v1 = epi[rl * 132 + cl + 1];
                *(uint*)&Cb[(size_t)grow * Nc + gcol] = (uint)f2bf(v0) | ((uint)f2bf(v1) << 16);
            }
        }
        __syncthreads();
    }
    if (OUT == 2) {
        if (rg == 1) {
            epi[colR * 4 + 0] = s0; epi[colR * 4 + 1] = s1;
            epi[colR * 4 + 2] = s2; epi[colR * 4 + 3] = s3;
        }
        __syncthreads();
        if (rg == 0) {
            s0 += epi[colR * 4 + 0]; s1 += epi[colR * 4 + 1];
            s2 += epi[colR * 4 + 2]; s3 += epi[colR * 4 + 3];
            int gcol = n0 + colR;
            if (gcol < Nc) {
                atomicAdd(&gsum[0 * Nc + gcol], s0);
                atomicAdd(&gsum[1 * Nc + gcol], s1);
                atomicAdd(&gsum[2 * Nc + gcol], s2);
                atomicAdd(&gsum[3 * Nc + gcol], s3);
            }
        }
    }
}

// ---------------- final: divide by precomputed group counts ----------------

__global__ void k_final(const float* __restrict__ gsum, const int* __restrict__ gcnt,
                        float* __restrict__ out) {
    int j = blockIdx.x * blockDim.x + threadIdx.x;
    if (j >= 800) return;
    int c = gcnt[j / 200];
    out[j] = (c > 0) ? gsum[j] / (float)c : 0.0f;
}

// ---------------- launch ----------------

extern "C" void kernel_launch(void* const* d_in, const int* in_sizes, int n_in,
                              void* d_out, int out_size, void* d_ws, size_t ws_size,
                              hipStream_t stream) {
    const float* x  = (const float*)d_in[0];
    const float* nf = (const float*)d_in[1];
    const int* ei   = (const int*)d_in[2];
    const float* W1 = (const float*)d_in[3];
    const float* b1 = (const float*)d_in[4];
    const float* W2 = (const float*)d_in[5];
    const float* b2 = (const float*)d_in[6];
    const float* W3 = (const float*)d_in[7];
    const float* b3 = (const float*)d_in[8];
    const float* W4 = (const float*)d_in[9];
    const float* b4 = (const float*)d_in[10];
    float* out = (float*)d_out;

    const int NN = in_sizes[0] / 100;  // 50000
    const int E  = in_sizes[2] / 2;    // 800000
    const int MPAD = ((NN + 127) / 128) * 128;  // 50048
    const int NB = (NN + 255) / 256;   // scan blocks (196 <= 256)
    const int PB = (NN + 3) / 4;       // prep blocks
    const int EB = (E + 255) / 256;    // deg/fill blocks
    const int TB = 1024;               // weight-split blocks
    const int* src = ei;
    const int* dst = ei + E;

    char* p = (char*)d_ws;
    auto alloc = [&](size_t bytes) -> char* {
        char* r = p;
        p += (bytes + 255) & ~(size_t)255;
        return r;
    };
    char* zz = p;
    int*   cnt  = (int*)alloc((size_t)NN * 4);   // packed: cnt3 lo16 | cntP hi16
    float* gsum = (float*)alloc(800 * 4);
    int*   gcnt = (int*)alloc(256);
    size_t zz_bytes = (size_t)(p - zz);
    int*   cnt3x = (int*)alloc((size_t)NN * 4);  // extracted cnt3 (scanA)
    int*   degT = (int*)alloc((size_t)NN * 4);
    int*   slot = (int*)alloc((size_t)E * 4);
    float* dinv = (float*)alloc((size_t)NN * 4);
    int*   offs = (int*)alloc((size_t)NN * 4);   // block-local prefix (scanA)
    int*   goffs = (int*)alloc((size_t)NN * 4);  // global prefix (fill)
    int*   bsum = (int*)alloc(1024);
    int*   gid  = (int*)alloc((size_t)NN * 4);
    unsigned char* gidb = (unsigned char*)alloc((size_t)NN);
    uint2* epk  = (uint2*)alloc((size_t)E * 8);
    ushort* WT1h = (ushort*)alloc((size_t)512 * 128 * 2);
    ushort* WT2h = (ushort*)alloc((size_t)256 * 512 * 2);
    ushort* WT3h = (ushort*)alloc((size_t)128 * 256 * 2);
    ushort* WT4h = (ushort*)alloc((size_t)256 * 128 * 2);
    ushort* xb = (ushort*)alloc((size_t)NN * 128 * 2);
    ushort* P1 = (ushort*)alloc((size_t)MPAD * 128 * 2);
    ushort* H1 = (ushort*)alloc((size_t)MPAD * 512 * 2);
    ushort* T2 = (ushort*)alloc((size_t)MPAD * 256 * 2);
    ushort* H2 = (ushort*)alloc((size_t)MPAD * 256 * 2);
    ushort* T3 = (ushort*)alloc((size_t)MPAD * 128 * 2);
    ushort* H3 = (ushort*)alloc((size_t)MPAD * 128 * 2);
    ushort* P4 = (ushort*)alloc((size_t)MPAD * 128 * 2);

    hipMemsetAsync(zz, 0, zz_bytes, stream);

    k_prepw<<<PB + TB, 256, 0, stream>>>((const uint*)x, (const uint*)nf, xb, gid, gidb, NN, PB,
        W1, W2, W3, W4, WT1h, WT2h, WT3h, WT4h);
    k_deg<<<EB, 256, 0, stream>>>(src, dst, E, gidb, cnt, slot);
    k_scanA<<<NB, 256, 0, stream>>>(cnt, cnt3x, degT, offs, bsum, dinv, gid, gcnt, NN);
    k_fill<<<EB, 256, 0, stream>>>(src, dst, slot, cnt3x, E, dinv, offs, bsum, epk, NN, NB, goffs);

    int aggBlocks = MPAD / 4;  // one wave per node (per slice)
    int mB = MPAD / 128;

    // P1 = agg(xb) -> bf16 [MPAD,128]; prototype shortcut (gather only type-3 srcs)
    k_agg1<<<aggBlocks, 256, 0, stream>>>(xb, nf, P1, dinv, goffs, degT, cnt3x, epk, NN, MPAD);
    // H1 = relu(P1 @ W1 + b1) -> bf16 [MPAD,512]
    k_gemm<true, 1><<<mB * 4, 256, 0, stream>>>(P1, WT1h, b1, H1, 512, 128, 4, nullptr, nullptr, 0);
    // T2 = H1 @ W2 -> bf16 [MPAD,256]
    k_gemm<false, 1><<<mB * 2, 256, 0, stream>>>(H1, WT2h, nullptr, T2, 256, 512, 2, nullptr, nullptr, 0);
    // H2 = relu(agg(T2) + b2) -> bf16 [MPAD,256], 2 XCD-pinned 128-col slices
    k_aggs<256, 2, true><<<aggBlocks * 2, 256, 0, stream>>>(T2, H2, dinv, goffs, degT, epk, b2, NN, MPAD);
    // T3 = H2 @ W3 -> bf16 [MPAD,128]
    k_gemm<false, 1><<<mB * 1, 256, 0, stream>>>(H2, WT3h, nullptr, T3, 128, 256, 1, nullptr, nullptr, 0);
    // H3 = relu(agg(T3) + b3) -> bf16 [MPAD,128]
    k_aggs<128, 1, true><<<aggBlocks, 256, 0, stream>>>(T3, H3, dinv, goffs, degT, epk, b3, NN, MPAD);
    // P4 = agg(H3) -> bf16 [MPAD,128]
    k_aggs<128, 1, false><<<aggBlocks, 256, 0, stream>>>(H3, P4, dinv, goffs, degT, epk, nullptr, NN, MPAD);
    // relu(P4 @ W4 + b4) -> per-group reduction into gsum (no H4 tensor)
    k_gemm<true, 2><<<mB * 2, 256, 0, stream>>>(P4, WT4h, b4, nullptr, 200, 128, 2, gid, gsum, NN);

    k_final<<<4, 256, 0, stream>>>(gsum, gcnt, out);
}

// Round 11
// 402.667 us; speedup vs baseline: 1.0829x; 1.0021x over previous
//
#include <hip/hip_runtime.h>
#include <stdint.h>

typedef __attribute__((ext_vector_type(8))) short bf16x8;
typedef __attribute__((ext_vector_type(4))) float f32x4;

__device__ __forceinline__ float bf2f(ushort h) {
    union { uint u; float f; } v; v.u = ((uint)h) << 16; return v.f;
}
__device__ __forceinline__ ushort f2bf(float f) {
    union { float f; uint u; } v; v.f = f;
    uint u = v.u;
    return (ushort)((u + 0x7fffu + ((u >> 16) & 1u)) >> 16);
}

// async global->LDS, 16B per lane; LDS dest = wave-uniform base + lane*16
__device__ __forceinline__ void gll(const ushort* g, ushort* l) {
    __builtin_amdgcn_global_load_lds(
        (const __attribute__((address_space(1))) void*)g,
        (__attribute__((address_space(3))) void*)l, 16, 0, 0);
}

// ---------------- prep+wsplit merged + workspace zeroing (no memset dispatch) ----------------
// r11: fold hipMemsetAsync into this kernel — prep waves zero their node's cnt;
// first wsplit blocks zero gsum/gcnt (consumed only after later dispatch
// boundaries, so ordering is guaranteed).

__device__ __forceinline__ void tr1_one(const float* __restrict__ W,
                                        ushort* __restrict__ WTh,
                                        int K, int Nc, int KP, int idx) {
    int n = idx / KP, k = idx % KP;
    float w = (n < Nc && k < K) ? W[(size_t)k * Nc + n] : 0.0f;
    WTh[idx] = f2bf(w);
}

__global__ void k_prepw(const uint* __restrict__ xu, const uint* __restrict__ nfu,
                        ushort* __restrict__ xb, int* __restrict__ gid,
                        unsigned char* __restrict__ gidb, int NN, int PB,
                        int* __restrict__ cnt, float* __restrict__ gsum,
                        int* __restrict__ gcnt,
                        const float* __restrict__ W1, const float* __restrict__ W2,
                        const float* __restrict__ W3, const float* __restrict__ W4,
                        ushort* __restrict__ WT1h, ushort* __restrict__ WT2h,
                        ushort* __restrict__ WT3h, ushort* __restrict__ WT4h) {
    int b = blockIdx.x;
    if (b < PB) {
        int wid = b * 4 + (threadIdx.x >> 6);
        int lane = threadIdx.x & 63;
        if (wid >= NN) return;
        int c0 = lane * 2;
        uint w = 0u;
        int m0 = 1, m1 = 1, m2 = 1;
        if (c0 < 100) {
            uint2 xv = *(const uint2*)&xu[(size_t)wid * 100 + c0];
            uint2 a = *(const uint2*)&nfu[c0];
            uint2 bb = *(const uint2*)&nfu[100 + c0];
            uint2 c = *(const uint2*)&nfu[200 + c0];
            m0 = (xv.x == a.x) & (xv.y == a.y);
            m1 = (xv.x == bb.x) & (xv.y == bb.y);
            m2 = (xv.x == c.x) & (xv.y == c.y);
            w = (uint)f2bf(__uint_as_float(xv.x)) | ((uint)f2bf(__uint_as_float(xv.y)) << 16);
        }
        int e0 = __all(m0), e1 = __all(m1), e2 = __all(m2);
        *(uint*)&xb[(size_t)wid * 128 + c0] = w;
        if (lane == 0) {
            cnt[wid] = 0;  // zeroed before k_deg (dispatch boundary guarantees)
            // group id for the output reduction: 0/3/1/2 mapping (unchanged)
            gid[wid] = e0 ? 0 : (e1 ? 3 : (e2 ? 1 : 2));
            // prototype id for agg1: 0,1,2 = nf row index, 3 = random features
            gidb[wid] = (unsigned char)(e0 ? 0 : (e1 ? 1 : (e2 ? 2 : 3)));
        }
    } else {
        int idx = (b - PB) * 256 + threadIdx.x;
        if (idx < 800) gsum[idx] = 0.0f;   // consumed by gemm4 (much later)
        if (idx < 4) gcnt[idx] = 0;        // consumed by scanA (later)
        if (idx < 65536) tr1_one(W1, WT1h, 100, 512, 128, idx);
        else if (idx < 196608) tr1_one(W2, WT2h, 512, 256, 512, idx - 65536);
        else if (idx < 229376) tr1_one(W3, WT3h, 256, 128, 256, idx - 196608);
        else if (idx < 262144) tr1_one(W4, WT4h, 128, 200, 128, idx - 229376);
    }
}

// ---------------- deg: ONE packed per-dst counter (cnt3 lo16 | cntP hi16) ----------------

__global__ void k_deg(const int* __restrict__ src, const int* __restrict__ dst, int E,
                      const unsigned char* __restrict__ gidb,
                      int* __restrict__ cnt, int* __restrict__ slot) {
    int e = blockIdx.x * 256 + threadIdx.x;
    if (e >= E) return;
    int d = dst[e];
    int t = gidb[src[e]];  // 50KB table, L2-hot
    uint inc = (t == 3) ? 1u : 0x10000u;
    uint old = (uint)atomicAdd(&cnt[d], (int)inc);
    int s = (t == 3) ? (int)(old & 0xffffu) : (int)(old >> 16);
    slot[e] = s | (t << 28);
}

// ---------------- scanA: block-local prefix + dinv + cnt3 extract + group counts ----------------

__global__ void k_scanA(const int* __restrict__ cnt,
                        int* __restrict__ cnt3x, int* __restrict__ degT,
                        int* __restrict__ offs,
                        int* __restrict__ bsum, float* __restrict__ dinv,
                        const int* __restrict__ gid, int* __restrict__ gcnt, int NN) {
    __shared__ int lds[256];
    __shared__ int cnt4[4];
    int t = threadIdx.x;
    if (t < 4) cnt4[t] = 0;
    int i = blockIdx.x * 256 + t;
    int v = 0;
    if (i < NN) {
        uint c = (uint)cnt[i];
        int d3 = (int)(c & 0xffffu);
        v = d3 + (int)(c >> 16);
        cnt3x[i] = d3;
        degT[i] = v;
        dinv[i] = 1.0f / sqrtf((float)(v + 1));  // +1 self loop
    }
    lds[t] = v;
    __syncthreads();
    if (i < NN) atomicAdd(&cnt4[gid[i]], 1);
    for (int d = 1; d < 256; d <<= 1) {
        int u = (t >= d) ? lds[t - d] : 0;
        __syncthreads();
        lds[t] += u;
        __syncthreads();
    }
    if (i < NN) offs[i] = lds[t] - v;  // block-local exclusive
    if (t == 255) bsum[blockIdx.x] = lds[255];
    __syncthreads();
    if (t < 4 && cnt4[t]) atomicAdd(&gcnt[t], cnt4[t]);
}

// ---------------- fill: atomic-free placement, class-segmented slots ----------------

__global__ void k_fill(const int* __restrict__ src, const int* __restrict__ dst,
                       const int* __restrict__ slot, const int* __restrict__ cnt3, int E,
                       const float* __restrict__ dinv, const int* __restrict__ offs,
                       const int* __restrict__ bsum,
                       uint2* __restrict__ epk, int NN, int NB,
                       int* __restrict__ goffs) {
    __shared__ int sex[256];
    int t = threadIdx.x;
    int v = (t < NB) ? bsum[t] : 0;
    sex[t] = v;
    __syncthreads();
    for (int d = 1; d < 256; d <<= 1) {
        int u = (t >= d) ? sex[t - d] : 0;
        __syncthreads();
        sex[t] += u;
        __syncthreads();
    }
    int incl = sex[t];
    __syncthreads();
    sex[t] = incl - v;  // exclusive prefix of bsum
    __syncthreads();
    int i = blockIdx.x * 256 + t;
    if (i < NN) goffs[i] = offs[i] + sex[i >> 8];
    if (i >= E) return;
    int s = src[i], d = dst[i];
    int sl = slot[i];
    int ty = sl >> 28;
    int sp = sl & 0x0FFFFFFF;
    int base = offs[d] + sex[d >> 8];
    int p = base + ((ty == 3) ? sp : (cnt3[d] + sp));
    epk[p] = make_uint2((uint)s | ((uint)ty << 30), __float_as_uint(dinv[s] * dinv[d]));
}

// ---------------- aggregation ----------------
// r2-r5: all agg variants pinned at time ~ total request bytes (E x row bytes)
// at ~7 TB/s delivered; r9: build phase at the same wall. Aggs frozen.
// epk.x carries src | (ptype<<30); mask with 0x3FFFFFFF when gathering.

__device__ __forceinline__ uint2 ldnt_u2(const uint2* p) {
    union { unsigned long long ll; uint2 v; } r;
    r.ll = __builtin_nontemporal_load((const unsigned long long*)p);
    return r.v;
}

__device__ __forceinline__ void fma2(uint u, float w, float& a0, float& a1) {
    union { uint u; float f; } lo, hi;
    lo.u = u << 16;           // bf16 low element -> f32
    hi.u = u & 0xffff0000u;   // bf16 high element -> f32
    a0 = fmaf(w, lo.f, a0);
    a1 = fmaf(w, hi.f, a1);
}

template <int UN, int LD>
__device__ __forceinline__ void agg_step(const ushort* __restrict__ Hc,
                                         const uint2* __restrict__ epk, int e,
                                         float& a0, float& a1) {
    uint2 q[UN];
#pragma unroll
    for (int i = 0; i < UN; ++i) q[i] = ldnt_u2(epk + e + i);
    uint u[UN];
#pragma unroll
    for (int i = 0; i < UN; ++i)
        u[i] = *(const uint*)(Hc + (size_t)(q[i].x & 0x3FFFFFFFu) * LD);
#pragma unroll
    for (int i = 0; i < UN; ++i) fma2(u[i], __uint_as_float(q[i].y), a0, a1);
}

// One wave per node per 128-col slice; slice = blockIdx % NSL (NSL | 8) pins
// slices to XCD classes (r4: cuts fetch 187->160MB, time-neutral; kept).
template <int LD, int NSL, bool BR>
__global__ __launch_bounds__(256) void k_aggs(
        const ushort* __restrict__ H, ushort* __restrict__ outb,
        const float* __restrict__ dinv, const int* __restrict__ offs,
        const int* __restrict__ deg, const uint2* __restrict__ epk,
        const float* __restrict__ bias, int NN, int NNpad) {
    int slice = (NSL > 1) ? (int)(blockIdx.x % NSL) : 0;
    int nb = (NSL > 1) ? (int)(blockIdx.x / NSL) : (int)blockIdx.x;
    int wv = threadIdx.x >> 6;
    int wid = nb * 4 + wv;
    int lane = threadIdx.x & 63;
    if (wid >= NNpad) return;
    int c0 = slice * 128 + lane * 2;
    ushort* op = outb + (size_t)wid * LD + c0;
    if (wid >= NN) {  // zero pad rows (this slice's 256B)
        __builtin_nontemporal_store(0u, (uint*)op);
        return;
    }
    const ushort* Hc = H + c0;
    float a0 = 0.0f, a1 = 0.0f;
    {   // self-loop term
        float di = dinv[wid];
        float sw = di * di;
        uint u = *(const uint*)(Hc + (size_t)wid * LD);
        fma2(u, sw, a0, a1);
    }
    int e = offs[wid];
    int end = e + deg[wid];
    for (; e + 16 <= end; e += 16) agg_step<16, LD>(Hc, epk, e, a0, a1);
    if (e + 8 <= end) { agg_step<8, LD>(Hc, epk, e, a0, a1); e += 8; }
    if (e + 4 <= end) { agg_step<4, LD>(Hc, epk, e, a0, a1); e += 4; }
    if (e + 2 <= end) { agg_step<2, LD>(Hc, epk, e, a0, a1); e += 2; }
    if (e < end) agg_step<1, LD>(Hc, epk, e, a0, a1);
    if (BR) {
        a0 = fmaxf(a0 + bias[c0], 0.0f);
        a1 = fmaxf(a1 + bias[c0 + 1], 0.0f);
    }
    uint w = (uint)f2bf(a0) | ((uint)f2bf(a1) << 16);
    __builtin_nontemporal_store(w, (uint*)op);
}

// ---------------- agg1: first-layer aggregation exploiting prototype rows ----------------

template <int UNB>
__device__ __forceinline__ void proto_step(const uint2* __restrict__ epk, int e,
                                           float& s0, float& s1, float& s2) {
    uint2 q[UNB];
#pragma unroll
    for (int i = 0; i < UNB; ++i) q[i] = ldnt_u2(epk + e + i);
#pragma unroll
    for (int i = 0; i < UNB; ++i) {
        int t = (int)(q[i].x >> 30);
        float w = __uint_as_float(q[i].y);
        s0 += (t == 0) ? w : 0.f;
        s1 += (t == 1) ? w : 0.f;
        s2 += (t == 2) ? w : 0.f;
    }
}

__global__ __launch_bounds__(256) void k_agg1(
        const ushort* __restrict__ H, const float* __restrict__ nf,
        ushort* __restrict__ outb,
        const float* __restrict__ dinv, const int* __restrict__ offs,
        const int* __restrict__ degT, const int* __restrict__ cnt3,
        const uint2* __restrict__ epk, int NN, int NNpad) {
    int wid = (int)((blockIdx.x * blockDim.x + threadIdx.x) >> 6);
    int lane = threadIdx.x & 63;
    if (wid >= NNpad) return;
    int c0 = lane * 2;
    ushort* op = outb + (size_t)wid * 128 + c0;
    if (wid >= NN) {
        __builtin_nontemporal_store(0u, (uint*)op);
        return;
    }
    const ushort* Hc = H + c0;
    float a0 = 0.0f, a1 = 0.0f;
    {   // self-loop term (xb holds bf16 features for ALL node types)
        float di = dinv[wid];
        float sw = di * di;
        uint u = *(const uint*)(Hc + (size_t)wid * 128);
        fma2(u, sw, a0, a1);
    }
    int beg = offs[wid];
    int d3 = cnt3[wid];
    int dT = degT[wid];
    // segment A: type-3 srcs -> gather (dense, full MLP)
    int e = beg, endA = beg + d3;
    for (; e + 8 <= endA; e += 8) agg_step<8, 128>(Hc, epk, e, a0, a1);
    if (e + 4 <= endA) { agg_step<4, 128>(Hc, epk, e, a0, a1); e += 4; }
    if (e + 2 <= endA) { agg_step<2, 128>(Hc, epk, e, a0, a1); e += 2; }
    if (e < endA) agg_step<1, 128>(Hc, epk, e, a0, a1);
    // segment B: proto srcs -> per-type norm sums (no gathers)
    float s0 = 0.f, s1 = 0.f, s2 = 0.f;
    e = endA;
    int endB = beg + dT;
    for (; e + 8 <= endB; e += 8) proto_step<8>(epk, e, s0, s1, s2);
    if (e + 4 <= endB) { proto_step<4>(epk, e, s0, s1, s2); e += 4; }
    if (e + 2 <= endB) { proto_step<2>(epk, e, s0, s1, s2); e += 2; }
    if (e < endB) proto_step<1>(epk, e, s0, s1, s2);
    // fold prototype contributions (bf16-roundtripped to match xb rows)
    if (c0 < 100) {
        float p00 = bf2f(f2bf(nf[c0]));
        float p01 = bf2f(f2bf(nf[c0 + 1]));
        float p10 = bf2f(f2bf(nf[100 + c0]));
        float p11 = bf2f(f2bf(nf[100 + c0 + 1]));
        float p20 = bf2f(f2bf(nf[200 + c0]));
        float p21 = bf2f(f2bf(nf[200 + c0 + 1]));
        a0 += s0 * p00 + s1 * p10 + s2 * p20;
        a1 += s0 * p01 + s1 * p11 + s2 * p21;
    }
    uint w = (uint)f2bf(a0) | ((uint)f2bf(a1) << 16);
    __builtin_nontemporal_store(w, (uint*)op);
}

// ---------------- MFMA GEMM: single-plane W, double-buffered counted-vmcnt ----------------
// r8: counted-vmcnt dbuf (+13.5us). r10: single-plane W (+18.5us). Frozen.

template <bool BR, int OUT>
__global__ __launch_bounds__(256) void k_gemm(
        const ushort* __restrict__ A, const ushort* __restrict__ Bh,
        const float* __restrict__ bias, ushort* __restrict__ Cb,
        int Nc, int K, int tNb,
        const int* __restrict__ gid, float* __restrict__ gsum, int NN) {
    __shared__ union {
        ushort st[2][2][128 * 32];  // [dbuf][plane A/B][row*32 + col] = 32KB
        float epi[64 * 132];
    } sm;
    __shared__ int gcode[64];
    int bm = blockIdx.x / tNb, bn = blockIdx.x % tNb;
    int m0 = bm * 128, n0 = bn * 128;
    int wv = threadIdx.x >> 6, lane = threadIdx.x & 63;
    int l15 = lane & 15, quad = lane >> 4;
    const ushort* gsrc;
    int plane, woff;
    if (wv == 0)      { gsrc = A  + (size_t)m0 * K;         plane = 0; woff = 0;    }
    else if (wv == 1) { gsrc = A  + (size_t)(m0 + 64) * K;  plane = 0; woff = 2048; }
    else if (wv == 2) { gsrc = Bh + (size_t)n0 * K;         plane = 1; woff = 0;    }
    else              { gsrc = Bh + (size_t)(n0 + 64) * K;  plane = 1; woff = 2048; }
    const ushort* gBase = gsrc + (size_t)(lane >> 2) * K + (lane & 3) * 8;
    ushort* lBase = &sm.st[0][0][0] + plane * 4096 + woff;
    const ushort* sAll = &sm.st[0][0][0];
    int wm = (wv >> 1) * 64, wn = (wv & 1) * 64;
    f32x4 acc[4][4] = {};
    int nk = K >> 5;
    // prologue: stage K-step 0 into buffer 0 (4 lines per wave)
    for (int i = 0; i < 4; ++i)
        gll(gBase + (size_t)(16 * i) * K, lBase + i * 512);
    for (int k = 0; k < nk; ++k) {
        int cur = k & 1;
        if (k + 1 < nk) {
            // issue next tile into the other buffer; do NOT wait for it
            ushort* l2 = lBase + (cur ^ 1) * 8192;
            const ushort* g2 = gBase + (k + 1) * 32;
            for (int i = 0; i < 4; ++i)
                gll(g2 + (size_t)(16 * i) * K, l2 + i * 512);
            asm volatile("s_waitcnt vmcnt(4)" ::: "memory");
        } else {
            asm volatile("s_waitcnt vmcnt(0)" ::: "memory");
        }
        __builtin_amdgcn_s_barrier();          // all waves' cur-buffer loads landed
        __builtin_amdgcn_sched_barrier(0);     // rule 18: pin reads below the wait
        const ushort* sA_ = sAll + cur * 8192;
        const ushort* sB_ = sA_ + 4096;
        bf16x8 Af[4], Bf[4];
#pragma unroll
        for (int i = 0; i < 4; ++i) {
            int ra = (wm + 16 * i + l15) * 32 + quad * 8;
            int rb = (wn + 16 * i + l15) * 32 + quad * 8;
            Af[i] = *(const bf16x8*)(sA_ + ra);
            Bf[i] = *(const bf16x8*)(sB_ + rb);
        }
#pragma unroll
        for (int mi = 0; mi < 4; ++mi)
#pragma unroll
            for (int ni = 0; ni < 4; ++ni)
                acc[mi][ni] = __builtin_amdgcn_mfma_f32_16x16x32_bf16(Af[mi], Bf[ni], acc[mi][ni], 0, 0, 0);
        __builtin_amdgcn_s_barrier();          // all waves done reading cur buffer
    }
    __builtin_amdgcn_sched_barrier(0);
    float bia[4] = {0.f, 0.f, 0.f, 0.f};
    if (BR) {
#pragma unroll
        for (int ni = 0; ni < 4; ++ni) {
            int col = n0 + wn + 16 * ni + l15;
            if (col < Nc) bia[ni] = bias[col];
        }
    }
    float* epi = sm.epi;
    int t = threadIdx.x;
    float s0 = 0.f, s1 = 0.f, s2 = 0.f, s3 = 0.f;  // OUT==2 per-group sums
    int colR = t & 127, rg = t >> 7;
    for (int half = 0; half < 2; ++half) {
        if ((wv >> 1) == half) {
#pragma unroll
            for (int mi = 0; mi < 4; ++mi)
#pragma unroll
                for (int r = 0; r < 4; ++r) {
                    int rl = mi * 16 + quad * 4 + r;
#pragma unroll
                    for (int ni = 0; ni < 4; ++ni) {
                        float v = acc[mi][ni][r];
                        if (BR) v = fmaxf(v + bia[ni], 0.0f);
                        epi[rl * 132 + wn + ni * 16 + l15] = v;
                    }
                }
        }
        if (OUT == 2 && t < 64) {
            int grow = m0 + half * 64 + t;
            gcode[t] = (grow < NN) ? gid[grow] : -1;
        }
        __syncthreads();
        if (OUT == 2) {
#pragma unroll 4
            for (int r = 0; r < 32; ++r) {
                int row = rg * 32 + r;
                int g = gcode[row];
                float v = epi[row * 132 + colR];
                s0 += (g == 0) ? v : 0.f;
                s1 += (g == 1) ? v : 0.f;
                s2 += (g == 2) ? v : 0.f;
                s3 += (g == 3) ? v : 0.f;
            }
        } else {
#pragma unroll
            for (int j = 0; j < 16; ++j) {
                int e = (j * 256 + t) * 2;
                int rl = e >> 7, cl = e & 127;
                int grow = m0 + half * 64 + rl;
                int gcol = n0 + cl;
                float v0 = epi[rl * 132 + cl];
                float v1 = epi[rl * 132 + cl + 1];
                *(uint*)&Cb[(size_t)grow * Nc + gcol] = (uint)f2bf(v0) | ((uint)f2bf(v1) << 16);
            }
        }
        __syncthreads();
    }
    if (OUT == 2) {
        if (rg == 1) {
            epi[colR * 4 + 0] = s0; epi[colR * 4 + 1] = s1;
            epi[colR * 4 + 2] = s2; epi[colR * 4 + 3] = s3;
        }
        __syncthreads();
        if (rg == 0) {
            s0 += epi[colR * 4 + 0]; s1 += epi[colR * 4 + 1];
            s2 += epi[colR * 4 + 2]; s3 += epi[colR * 4 + 3];
            int gcol = n0 + colR;
            if (gcol < Nc) {
                atomicAdd(&gsum[0 * Nc + gcol], s0);
                atomicAdd(&gsum[1 * Nc + gcol], s1);
                atomicAdd(&gsum[2 * Nc + gcol], s2);
                atomicAdd(&gsum[3 * Nc + gcol], s3);
            }
        }
    }
}

// ---------------- final: divide by precomputed group counts ----------------

__global__ void k_final(const float* __restrict__ gsum, const int* __restrict__ gcnt,
                        float* __restrict__ out) {
    int j = blockIdx.x * blockDim.x + threadIdx.x;
    if (j >= 800) return;
    int c = gcnt[j / 200];
    out[j] = (c > 0) ? gsum[j] / (float)c : 0.0f;
}

// ---------------- launch ----------------

extern "C" void kernel_launch(void* const* d_in, const int* in_sizes, int n_in,
                              void* d_out, int out_size, void* d_ws, size_t ws_size,
                              hipStream_t stream) {
    const float* x  = (const float*)d_in[0];
    const float* nf = (const float*)d_in[1];
    const int* ei   = (const int*)d_in[2];
    const float* W1 = (const float*)d_in[3];
    const float* b1 = (const float*)d_in[4];
    const float* W2 = (const float*)d_in[5];
    const float* b2 = (const float*)d_in[6];
    const float* W3 = (const float*)d_in[7];
    const float* b3 = (const float*)d_in[8];
    const float* W4 = (const float*)d_in[9];
    const float* b4 = (const float*)d_in[10];
    float* out = (float*)d_out;

    const int NN = in_sizes[0] / 100;  // 50000
    const int E  = in_sizes[2] / 2;    // 800000
    const int MPAD = ((NN + 127) / 128) * 128;  // 50048
    const int NB = (NN + 255) / 256;   // scan blocks (196 <= 256)
    const int PB = (NN + 3) / 4;       // prep blocks
    const int EB = (E + 255) / 256;    // deg/fill blocks
    const int TB = 1024;               // weight-split blocks
    const int* src = ei;
    const int* dst = ei + E;

    char* p = (char*)d_ws;
    auto alloc = [&](size_t bytes) -> char* {
        char* r = p;
        p += (bytes + 255) & ~(size_t)255;
        return r;
    };
    int*   cnt  = (int*)alloc((size_t)NN * 4);   // packed: cnt3 lo16 | cntP hi16 (zeroed in k_prepw)
    float* gsum = (float*)alloc(800 * 4);        // zeroed in k_prepw
    int*   gcnt = (int*)alloc(256);              // zeroed in k_prepw
    int*   cnt3x = (int*)alloc((size_t)NN * 4);  // extracted cnt3 (scanA)
    int*   degT = (int*)alloc((size_t)NN * 4);
    int*   slot = (int*)alloc((size_t)E * 4);
    float* dinv = (float*)alloc((size_t)NN * 4);
    int*   offs = (int*)alloc((size_t)NN * 4);   // block-local prefix (scanA)
    int*   goffs = (int*)alloc((size_t)NN * 4);  // global prefix (fill)
    int*   bsum = (int*)alloc(1024);
    int*   gid  = (int*)alloc((size_t)NN * 4);
    unsigned char* gidb = (unsigned char*)alloc((size_t)NN);
    uint2* epk  = (uint2*)alloc((size_t)E * 8);
    ushort* WT1h = (ushort*)alloc((size_t)512 * 128 * 2);
    ushort* WT2h = (ushort*)alloc((size_t)256 * 512 * 2);
    ushort* WT3h = (ushort*)alloc((size_t)128 * 256 * 2);
    ushort* WT4h = (ushort*)alloc((size_t)256 * 128 * 2);
    ushort* xb = (ushort*)alloc((size_t)NN * 128 * 2);
    ushort* P1 = (ushort*)alloc((size_t)MPAD * 128 * 2);
    ushort* H1 = (ushort*)alloc((size_t)MPAD * 512 * 2);
    ushort* T2 = (ushort*)alloc((size_t)MPAD * 256 * 2);
    ushort* H2 = (ushort*)alloc((size_t)MPAD * 256 * 2);
    ushort* T3 = (ushort*)alloc((size_t)MPAD * 128 * 2);
    ushort* H3 = (ushort*)alloc((size_t)MPAD * 128 * 2);
    ushort* P4 = (ushort*)alloc((size_t)MPAD * 128 * 2);

    k_prepw<<<PB + TB, 256, 0, stream>>>((const uint*)x, (const uint*)nf, xb, gid, gidb, NN, PB,
        cnt, gsum, gcnt,
        W1, W2, W3, W4, WT1h, WT2h, WT3h, WT4h);
    k_deg<<<EB, 256, 0, stream>>>(src, dst, E, gidb, cnt, slot);
    k_scanA<<<NB, 256, 0, stream>>>(cnt, cnt3x, degT, offs, bsum, dinv, gid, gcnt, NN);
    k_fill<<<EB, 256, 0, stream>>>(src, dst, slot, cnt3x, E, dinv, offs, bsum, epk, NN, NB, goffs);

    int aggBlocks = MPAD / 4;  // one wave per node (per slice)
    int mB = MPAD / 128;

    // P1 = agg(xb) -> bf16 [MPAD,128]; prototype shortcut (gather only type-3 srcs)
    k_agg1<<<aggBlocks, 256, 0, stream>>>(xb, nf, P1, dinv, goffs, degT, cnt3x, epk, NN, MPAD);
    // H1 = relu(P1 @ W1 + b1) -> bf16 [MPAD,512]
    k_gemm<true, 1><<<mB * 4, 256, 0, stream>>>(P1, WT1h, b1, H1, 512, 128, 4, nullptr, nullptr, 0);
    // T2 = H1 @ W2 -> bf16 [MPAD,256]
    k_gemm<false, 1><<<mB * 2, 256, 0, stream>>>(H1, WT2h, nullptr, T2, 256, 512, 2, nullptr, nullptr, 0);
    // H2 = relu(agg(T2) + b2) -> bf16 [MPAD,256], 2 XCD-pinned 128-col slices
    k_aggs<256, 2, true><<<aggBlocks * 2, 256, 0, stream>>>(T2, H2, dinv, goffs, degT, epk, b2, NN, MPAD);
    // T3 = H2 @ W3 -> bf16 [MPAD,128]
    k_gemm<false, 1><<<mB * 1, 256, 0, stream>>>(H2, WT3h, nullptr, T3, 128, 256, 1, nullptr, nullptr, 0);
    // H3 = relu(agg(T3) + b3) -> bf16 [MPAD,128]
    k_aggs<128, 1, true><<<aggBlocks, 256, 0, stream>>>(T3, H3, dinv, goffs, degT, epk, b3, NN, MPAD);
    // P4 = agg(H3) -> bf16 [MPAD,128]
    k_aggs<128, 1, false><<<aggBlocks, 256, 0, stream>>>(H3, P4, dinv, goffs, degT, epk, nullptr, NN, MPAD);
    // relu(P4 @ W4 + b4) -> per-group reduction into gsum (no H4 tensor)
    k_gemm<true, 2><<<mB * 2, 256, 0, stream>>>(P4, WT4h, b4, nullptr, 200, 128, 2, gid, gsum, NN);

    k_final<<<4, 256, 0, stream>>>(gsum, gcnt, out);
}